// Round 3
// baseline (4043.179 us; speedup 1.0000x reference)
//
#include <hip/hip_runtime.h>

// EventTransformer on MI355X. B=2, N=8192, C=CN=64, M=16, H=180, W=240.
// Internal compute fp32 in d_ws (~13.25 MB, batches sequential).
// I/O dtype (fp32 vs bf16) detected at runtime from events word 3 (p0 == +-1.0f
// exactly iff fp32). All input loads / output stores go through ld()/stout().
//
// Algebra:
//  local attn : logits[n,m] = ac[n] - t[n+m-8]; S[m] = Vsum - excl_v(m) + excl_f(m)
//  global attn: scores n-independent -> gx_sa is one 64-vec per batch; gx_Wq unused.

typedef unsigned short u16;

#define NB 8192
#define NBATCH 2
#define IMG_H 180
#define IMG_W 240
#define HWPIX (IMG_H*IMG_W)          // 43200
#define SPB (HWPIX*64)               // 2,764,800 floats (one batch image)
#define NC (NB*64)                   // 524,288

// float-element offsets into ws (per-batch reuse; A,C alias front of SPACE)
#define OFF_SPACE 0
#define OFF_A     0                  // lx_in -> kg  (dead before space zero)
#define OFF_C     NC                 // vg           (dead before space zero)
#define OFF_B     SPB                // lx_out       (lives through kImg)
#define SMB       (SPB + NC)         // 3,289,088
#define OFF_AC    (SMB)
#define OFF_T     (SMB + 8192)
#define OFF_ZERO  (SMB + 16384)      // VSUM 64 | LXSUM 64 | STATS 16
#define OFF_VSUM  (OFF_ZERO)
#define OFF_LXSUM (OFF_ZERO + 64)
#define OFF_STATS (OFF_ZERO + 128)
#define ZERO_CNT  144
#define OFF_S     (SMB + 16544)      // 16*64
#define OFF_SEL   (SMB + 17568)      // 3*16*64
#define OFF_CG    (SMB + 20640)      // 64
#define OFF_W1    (SMB + 20704)      // 192
#define OFF_EDGEV (SMB + 20896)      // 16*64
#define OFF_EDGEF (SMB + 21920)      // 16*64
#define WS_FLOATS (SMB + 22944)      // 3,312,032 floats = 13,248,128 bytes

__device__ __forceinline__ float bf2f(u16 u){
  union { unsigned int i; float f; } w; w.i = ((unsigned int)u) << 16; return w.f;
}
__device__ __forceinline__ u16 f2bf(float f){
  union { unsigned int i; float f; } w; w.f = f;
  unsigned int x = w.i;
  x += 0x7fffu + ((x >> 16) & 1u);   // RNE
  return (u16)(x >> 16);
}
// dtype detect: events[3] (= p0) is exactly +-1.0f iff buffers are fp32
__device__ __forceinline__ bool isbf(const void* ev){
  unsigned w3 = ((const unsigned*)ev)[3];
  return !(w3 == 0x3F800000u || w3 == 0xBF800000u);
}
__device__ __forceinline__ float ld(const void* p, int i, bool bf){
  return bf ? bf2f(((const u16*)p)[i]) : ((const float*)p)[i];
}
__device__ __forceinline__ void stout(void* o, long i, float v, bool bf){
  if (bf) ((u16*)o)[i] = f2bf(v); else ((float*)o)[i] = v;
}
__device__ __forceinline__ float waveSum(float v){
#pragma unroll
  for (int m = 1; m < 64; m <<= 1) v += __shfl_xor(v, m, 64);
  return v;
}

// ---- zero helpers (no hipMemsetAsync -> zero graph-capture risk)
__global__ void kZeroSmall(float* __restrict__ ws){
  if (threadIdx.x < ZERO_CNT) ws[OFF_ZERO + threadIdx.x] = 0.f;
}
__global__ void kZeroSpace(float* __restrict__ ws){
  float4 z = make_float4(0.f, 0.f, 0.f, 0.f);
  ((float4*)(ws + OFF_SPACE))[blockIdx.x*256 + threadIdx.x] = z;
}

// ---- kW: wq1 = Wq@Wsa1, wk1 = Wk@Wsa1, wpe1 = Wpe@Wsa1 (once)
__global__ void kW(const void* __restrict__ ev, const void* __restrict__ Wq,
                   const void* __restrict__ Wk, const void* __restrict__ Wpe,
                   const void* __restrict__ w1, float* __restrict__ ws){
  const bool bf = isbf(ev);
  const int lane = threadIdx.x;  // 64
  float s1 = 0.f, s2 = 0.f;
  for (int c = 0; c < 64; c++){
    float wc = ld(w1, c, bf);
    s1 += ld(Wq, lane*64 + c, bf) * wc;
    s2 += ld(Wk, lane*64 + c, bf) * wc;
  }
  ws[OFF_W1 + lane] = s1;
  ws[OFF_W1 + 64 + lane] = s2;
  if (lane < 4){
    float s3 = 0.f;
    for (int c = 0; c < 64; c++) s3 += ld(Wpe, lane*64 + c, bf) * ld(w1, c, bf);
    ws[OFF_W1 + 128 + lane] = s3;
  }
}

// ---- kA: per row lx_in (stored), scalars ac,t; Vsum atomic; edge v/f stored
__global__ void __launch_bounds__(256) kA(const void* __restrict__ ev,
    const void* __restrict__ Wm, const void* __restrict__ Wpe,
    const void* __restrict__ Wv, float* __restrict__ ws, int b){
  const bool bf = isbf(ev);
  const int lane = threadIdx.x & 63, w = threadIdx.x >> 6;
  const float wq1 = ws[OFF_W1 + lane];
  const float wk1 = ws[OFF_W1 + 64 + lane];
  const float wp10 = ws[OFF_W1+128], wp11 = ws[OFF_W1+129],
              wp12 = ws[OFF_W1+130], wp13 = ws[OFF_W1+131];
  float wmc[4], wpc[4], wvc[64];
#pragma unroll
  for (int j = 0; j < 4; j++){ wmc[j] = ld(Wm, j*64+lane, bf); wpc[j] = ld(Wpe, j*64+lane, bf); }
#pragma unroll
  for (int cn = 0; cn < 64; cn++) wvc[cn] = ld(Wv, cn*64+lane, bf);
  float vsum = 0.f;
  for (int i = 0; i < 32; i++){
    const int n = blockIdx.x*128 + w + 4*i;
    const int e4 = (b*NB + n)*4;
    float e0 = ld(ev, e4+0, bf), e1 = ld(ev, e4+1, bf),
          e2 = ld(ev, e4+2, bf), e3 = ld(ev, e4+3, bf);
    float lx = e0*wmc[0] + e1*wmc[1] + e2*wmc[2] + e3*wmc[3];
    float v = 0.f;
#pragma unroll
    for (int cn = 0; cn < 64; cn++) v += __shfl(lx, cn, 64) * wvc[cn];
    float epe = e0*wp10 + e1*wp11 + e2*wp12 + e3*wp13;
    float acv = waveSum(lx * wq1) + epe;
    float tv  = waveSum(lx * wk1) + epe;
    ws[OFF_A + n*64 + lane] = lx;
    if (lane == 0){ ws[OFF_AC + n] = acv; ws[OFF_T + n] = tv; }
    if (n < 8 || n >= NB-8){
      int e = (n < 8) ? n : (n - (NB-16));
      float f = e0*wpc[0] + e1*wpc[1] + e2*wpc[2] + e3*wpc[3];
      ws[OFF_EDGEV + e*64 + lane] = v;
      ws[OFF_EDGEF + e*64 + lane] = f;
    }
    vsum += v;
  }
  atomicAdd(&ws[OFF_VSUM + lane], vsum);
}

// ---- kB: S[m,c] = Vsum[c] - excl_v(m) + excl_f(m)
__global__ void __launch_bounds__(64) kB(float* __restrict__ ws){
  const int m = blockIdx.x, lane = threadIdx.x;
  const int d = m - 8;
  float sv = 0.f, sf = 0.f;
  if (d < 0){
    for (int e = 16 + d; e < 16; e++){
      sv += ws[OFF_EDGEV + e*64 + lane];
      sf += ws[OFF_EDGEF + e*64 + lane];
    }
  } else {
    for (int e = 0; e < d; e++){
      sv += ws[OFF_EDGEV + e*64 + lane];
      sf += ws[OFF_EDGEF + e*64 + lane];
    }
  }
  ws[OFF_S + m*64 + lane] = ws[OFF_VSUM + lane] - sv + sf;
}

// ---- kC: softmax over m, lx_out = lx_in + (scores@S)@Wsa2; kg,vg projections
__global__ void __launch_bounds__(256) kC(const void* __restrict__ ev,
    const void* __restrict__ Wsa2, const void* __restrict__ gWk,
    const void* __restrict__ gWv, float* __restrict__ ws){
  const bool bf = isbf(ev);
  __shared__ float S_lds[1024];
  const int tid = threadIdx.x, lane = tid & 63, w = tid >> 6;
  for (int i = tid; i < 1024; i += 256) S_lds[i] = ws[OFF_S + i];
  __syncthreads();
  float lxsum = 0.f;
  for (int i = 0; i < 32; i++){
    const int n = blockIdx.x*128 + w + 4*i;
    float lx  = ws[OFF_A + n*64 + lane];
    float acn = ws[OFF_AC + n];
    const int m = lane & 15;
    const int j = n + m - 8;
    float tv = (j >= 0 && j < NB) ? ws[OFF_T + j] : 0.f;
    float logit = acn - tv;
    float mx = logit;
#pragma unroll
    for (int k = 1; k < 16; k <<= 1) mx = fmaxf(mx, __shfl_xor(mx, k, 64));
    float ex = expf(logit - mx);
    float sm = ex;
#pragma unroll
    for (int k = 1; k < 16; k <<= 1) sm += __shfl_xor(sm, k, 64);
    float sig = ex / sm;
    float pat = 0.f;
#pragma unroll
    for (int mm = 0; mm < 16; mm++) pat += __shfl(sig, mm, 64) * S_lds[mm*64 + lane];
    float sa = 0.f;
#pragma unroll
    for (int cn = 0; cn < 64; cn++) sa += __shfl(pat, cn, 64) * ld(Wsa2, cn*64 + lane, bf);
    float lxo = lx + sa;
    float kg = 0.f, vg = 0.f;
#pragma unroll
    for (int cn = 0; cn < 64; cn++){
      float a = __shfl(lxo, cn, 64);
      kg += a * ld(gWk, cn*64 + lane, bf);
      vg += a * ld(gWv, cn*64 + lane, bf);
    }
    ws[OFF_B + n*64 + lane] = lxo;
    ws[OFF_A + n*64 + lane] = kg;
    ws[OFF_C + n*64 + lane] = vg;
    lxsum += lxo;
  }
  atomicAdd(&ws[OFF_LXSUM + lane], lxsum);
}

// ---- FPS: exact reference replication; blockIdx.x = {0:lx_out,1:kg,2:vg}
__device__ __forceinline__ float dist64(const float* __restrict__ p, const float4* cr){
  const float4* p4 = (const float4*)p;
  float d = 0.f;
#pragma unroll
  for (int i = 0; i < 16; i++){
    float4 a = p4[i]; float4 c = cr[i];
    float dx = a.x - c.x, dy = a.y - c.y, dz = a.z - c.z, dw = a.w - c.w;
    d += dx*dx; d += dy*dy; d += dz*dz; d += dw*dw;
  }
  return d;
}

__global__ void __launch_bounds__(512) kFPS(float* __restrict__ ws){
  __shared__ float cent[64];
  __shared__ float red[8*64];
  __shared__ float swv[8];
  __shared__ int   swi[8];
  __shared__ int   sel[16];
  __shared__ int   curIdx;
  const int arr = blockIdx.x;
  const float* pts = ws + (arr == 0 ? OFF_B : arr == 1 ? OFF_A : OFF_C);
  const int tid = threadIdx.x, lane = tid & 63, w = tid >> 6;

  { // barycenter
    const int c = tid & 63, g = tid >> 6;
    float s = 0.f;
    for (int n = g; n < NB; n += 8) s += pts[n*64 + c];
    red[g*64 + c] = s;
    __syncthreads();
    if (tid < 64){
      float t = 0.f;
#pragma unroll
      for (int q = 0; q < 8; q++) t += red[q*64 + tid];
      cent[tid] = t * (1.0f/NB);
    }
    __syncthreads();
  }
  float4 cr[16];
#pragma unroll
  for (int i = 0; i < 16; i++) cr[i] = ((const float4*)cent)[i];

  float bv = -1e30f; int bi = 0;
  for (int j = 0; j < 16; j++){
    int n = tid + 512*j;
    float d = dist64(pts + n*64, cr);
    if (d > bv){ bv = d; bi = n; }
  }
#pragma unroll
  for (int o = 1; o < 64; o <<= 1){
    float ov = __shfl_xor(bv, o, 64); int oi = __shfl_xor(bi, o, 64);
    if (ov > bv || (ov == bv && oi < bi)){ bv = ov; bi = oi; }
  }
  if (lane == 0){ swv[w] = bv; swi[w] = bi; }
  __syncthreads();
  if (tid == 0){
    float Bv = swv[0]; int Iv = swi[0];
#pragma unroll
    for (int q = 1; q < 8; q++) if (swv[q] > Bv || (swv[q] == Bv && swi[q] < Iv)){ Bv = swv[q]; Iv = swi[q]; }
    curIdx = Iv;
  }
  __syncthreads();

  float md[16];
#pragma unroll
  for (int j = 0; j < 16; j++) md[j] = 1e10f;

  for (int it = 0; it < 16; it++){
    int ci = curIdx;
    if (tid == 0) sel[it] = ci;
    if (tid < 64) cent[tid] = pts[ci*64 + tid];
    __syncthreads();
#pragma unroll
    for (int i = 0; i < 16; i++) cr[i] = ((const float4*)cent)[i];
    bv = -1e30f; bi = 0;
    for (int j = 0; j < 16; j++){
      int n = tid + 512*j;
      float d = dist64(pts + n*64, cr);
      float m2 = fminf(md[j], d);
      md[j] = m2;
      if (m2 > bv){ bv = m2; bi = n; }
    }
#pragma unroll
    for (int o = 1; o < 64; o <<= 1){
      float ov = __shfl_xor(bv, o, 64); int oi = __shfl_xor(bi, o, 64);
      if (ov > bv || (ov == bv && oi < bi)){ bv = ov; bi = oi; }
    }
    if (lane == 0){ swv[w] = bv; swi[w] = bi; }
    __syncthreads();
    if (tid == 0){
      float Bv = swv[0]; int Iv = swi[0];
#pragma unroll
      for (int q = 1; q < 8; q++) if (swv[q] > Bv || (swv[q] == Bv && swi[q] < Iv)){ Bv = swv[q]; Iv = swi[q]; }
      curIdx = Iv;
    }
    __syncthreads();
  }
  if (tid == 0){
    for (int i = 1; i < 16; i++){
      int key = sel[i]; int j = i - 1;
      while (j >= 0 && sel[j] > key){ sel[j+1] = sel[j]; j--; }
      sel[j+1] = key;
    }
  }
  __syncthreads();
  for (int idx = tid; idx < 1024; idx += 512){
    int m = idx >> 6;
    ws[OFF_SEL + arr*1024 + idx] = pts[sel[m]*64 + (idx & 63)];
  }
}

// ---- kG: per-batch constant gx_sa vector
__global__ void kG(const void* __restrict__ ev, const void* __restrict__ gWpe,
                   const void* __restrict__ gWsa1, const void* __restrict__ gWsa2,
                   float* __restrict__ ws){
  const bool bf = isbf(ev);
  __shared__ float gf[16*64];
  __shared__ float beta[16];
  const int lane = threadIdx.x;  // 64
  const float gw1 = ld(gWsa1, lane, bf);
  float wpec[64];
#pragma unroll
  for (int cn = 0; cn < 64; cn++) wpec[cn] = ld(gWpe, cn*64 + lane, bf);
  float lxs = ws[OFF_LXSUM + lane];
  float G = 0.f;
#pragma unroll
  for (int cn = 0; cn < 64; cn++) G += __shfl(lxs, cn, 64) * wpec[cn];
  const float* selp = ws + OFF_SEL;
  for (int m = 0; m < 16; m++){
    float plx = selp[m*64 + lane];            // fps(lx_out)
    float g = 0.f;
#pragma unroll
    for (int cn = 0; cn < 64; cn++) g += __shfl(plx, cn, 64) * wpec[cn];
    gf[m*64 + lane] = g;
    float pk = selp[1024 + m*64 + lane];      // fps(kg)
    float part = waveSum((pk + g) * gw1);
    if (lane == 0) beta[m] = part;
  }
  __syncthreads();
  float mx = -1e30f;
  for (int m = 0; m < 16; m++) mx = fmaxf(mx, -beta[m]);
  float ssum = 0.f;
  for (int m = 0; m < 16; m++) ssum += expf(-beta[m] - mx);
  float A = 0.f;
  for (int m = 0; m < 16; m++){
    float sg = expf(-beta[m] - mx) / ssum;
    float pv = selp[2048 + m*64 + lane];      // fps(vg)
    float Sg = 8192.0f * (pv - gf[m*64 + lane]) + G;
    A += sg * Sg;
  }
  float cg = 0.f;
#pragma unroll
  for (int cn = 0; cn < 64; cn++) cg += __shfl(A, cn, 64) * ld(gWsa2, cn*64 + lane, bf);
  ws[OFF_CG + lane] = cg;
}

// ---- kImg: LN + exact GELU + scatter-add into space (index clamped)
__global__ void __launch_bounds__(256) kImg(const void* __restrict__ ev,
    const void* __restrict__ lnw, const void* __restrict__ lnb,
    float* __restrict__ ws, int b){
  const bool bf = isbf(ev);
  const int lane = threadIdx.x & 63, w = threadIdx.x >> 6;
  const float cg = ws[OFF_CG + lane];
  const float lw = ld(lnw, lane, bf), lb = ld(lnb, lane, bf);
  float* space = ws + OFF_SPACE;
  for (int i = 0; i < 32; i++){
    const int n = blockIdx.x*128 + w + 4*i;
    float x = ws[OFF_B + n*64 + lane] + cg;
    float mu = waveSum(x) * (1.0f/64.0f);
    float dv = x - mu;
    float var = waveSum(dv*dv) * (1.0f/64.0f);
    float xn = dv / sqrtf(var + 1e-5f);
    float y = xn * lw + lb;
    float h = 0.5f * y * (1.0f + erff(y * 0.70710678118654752f));
    const int e4 = (b*NB + n)*4;
    float exf = ld(ev, e4+0, bf), eyf = ld(ev, e4+1, bf), epf = ld(ev, e4+3, bf);
    int xi = (int)floorf(exf), yi = (int)floorf(eyf);
    int flat = yi*IMG_W + xi;
    flat = max(0, min(HWPIX-1, flat));   // guard: fault -> absmax signal
    atomicAdd(space + flat*64 + lane, epf * h);
  }
}

// ---- stats pass 1: count nonzero + sum
__global__ void __launch_bounds__(256) kStat1(float* __restrict__ ws){
  const float* sp = ws + OFF_SPACE;
  float cnt = 0.f, sum = 0.f;
  for (unsigned i = blockIdx.x*256u + threadIdx.x; i < SPB; i += gridDim.x*256u){
    float x = sp[i];
    if (x != 0.f){ cnt += 1.f; sum += x; }
  }
  cnt = waveSum(cnt); sum = waveSum(sum);
  __shared__ float rc[4], rs[4];
  const int lane = threadIdx.x & 63, w = threadIdx.x >> 6;
  if (lane == 0){ rc[w] = cnt; rs[w] = sum; }
  __syncthreads();
  if (threadIdx.x == 0){
    atomicAdd(&ws[OFF_STATS + 0], rc[0]+rc[1]+rc[2]+rc[3]);
    atomicAdd(&ws[OFF_STATS + 1], rs[0]+rs[1]+rs[2]+rs[3]);
  }
}

// ---- stats pass 2: masked sum of (x-mean)^2
__global__ void __launch_bounds__(256) kStat2(float* __restrict__ ws){
  const float cnt = ws[OFF_STATS + 0];
  const float sum = ws[OFF_STATS + 1];
  const float mean = sum / fmaxf(cnt, 1.f);
  const float* sp = ws + OFF_SPACE;
  float m2 = 0.f;
  for (unsigned i = blockIdx.x*256u + threadIdx.x; i < SPB; i += gridDim.x*256u){
    float x = sp[i];
    if (x != 0.f){ float d = x - mean; m2 += d*d; }
  }
  m2 = waveSum(m2);
  __shared__ float rm[4];
  const int lane = threadIdx.x & 63, w = threadIdx.x >> 6;
  if (lane == 0) rm[w] = m2;
  __syncthreads();
  if (threadIdx.x == 0) atomicAdd(&ws[OFF_STATS + 2], rm[0]+rm[1]+rm[2]+rm[3]);
}

// ---- output: normalize + transpose (h,w,c)->(c,h,w), dtype-matched store
__global__ void __launch_bounds__(256) kOut(const void* __restrict__ ev,
    const float* __restrict__ ws, void* __restrict__ out, int b){
  const bool bf = isbf(ev);
  const int c = blockIdx.y;
  const int hw = blockIdx.x*256 + threadIdx.x;
  if (hw >= HWPIX) return;
  const float cnt = ws[OFF_STATS + 0];
  const float sum = ws[OFF_STATS + 1];
  const float m2  = ws[OFF_STATS + 2];
  const float mean = sum / fmaxf(cnt, 1.f);
  const float var  = m2 / fmaxf(cnt - 1.f, 1.f);
  const float stdv = sqrtf(var);
  float x = ws[OFF_SPACE + hw*64 + c];
  float centered = (x != 0.f) ? (x - mean) : x;
  float normed = (stdv > 0.f) ? (centered / stdv) : centered;
  float o = (cnt > 0.f) ? normed : x;
  stout(out, (long)(b*64 + c)*HWPIX + hw, o, bf);
}

extern "C" void kernel_launch(void* const* d_in, const int* in_sizes, int n_in,
                              void* d_out, int out_size, void* d_ws, size_t ws_size,
                              hipStream_t stream){
  (void)in_sizes; (void)n_in; (void)out_size; (void)ws_size;
  const void* ev     = d_in[0];
  const void* Wm     = d_in[1];
  const void* Wpe    = d_in[2];
  const void* lnw    = d_in[3];
  const void* lnb    = d_in[4];
  const void* lxWq   = d_in[5];
  const void* lxWk   = d_in[6];
  const void* lxWv   = d_in[7];
  const void* lxWsa1 = d_in[8];
  const void* lxWsa2 = d_in[9];
  // d_in[10] = gx_Wq : unused (cancels in n-independent softmax)
  const void* gxWk   = d_in[11];
  const void* gxWv   = d_in[12];
  const void* gxWpe  = d_in[13];
  const void* gxWsa1 = d_in[14];
  const void* gxWsa2 = d_in[15];
  float* ws = (float*)d_ws;

  kW<<<1, 64, 0, stream>>>(ev, lxWq, lxWk, Wpe, lxWsa1, ws);
  for (int b = 0; b < NBATCH; b++){
    kZeroSmall<<<1, 256, 0, stream>>>(ws);
    kA<<<64, 256, 0, stream>>>(ev, Wm, Wpe, lxWv, ws, b);
    kB<<<16, 64, 0, stream>>>(ws);
    kC<<<64, 256, 0, stream>>>(ev, lxWsa2, gxWk, gxWv, ws);
    kFPS<<<3, 512, 0, stream>>>(ws);
    kG<<<1, 64, 0, stream>>>(ev, gxWpe, gxWsa1, gxWsa2, ws);
    kZeroSpace<<<SPB/4/256, 256, 0, stream>>>(ws);
    kImg<<<64, 256, 0, stream>>>(ev, lnw, lnb, ws, b);
    kStat1<<<256, 256, 0, stream>>>(ws);
    kStat2<<<256, 256, 0, stream>>>(ws);
    kOut<<<dim3((HWPIX+255)/256, 64), 256, 0, stream>>>(ev, ws, d_out, b);
  }
}

// Round 4
// 1034.056 us; speedup vs baseline: 3.9100x; 3.9100x over previous
//
#include <hip/hip_runtime.h>

// EventTransformer on MI355X. B=2, N=8192, C=CN=64, M=16, H=180, W=240.
// fp32 internal in d_ws (~13.3 MB, batches sequential). I/O dtype (fp32/bf16)
// runtime-detected from events word 3 (p0 == +-1.0f exactly iff fp32).
//
// R4: kFPS rewritten as 16-block-per-array persistent kernel w/ register-resident
// points + spin grid barriers (monotonic counters). kB folded into kC; kG folded
// into kFPS tail. kC weights register-resident (3-pass).

typedef unsigned short u16;
typedef unsigned long long ull;

#define NB 8192
#define NBATCH 2
#define IMG_H 180
#define IMG_W 240
#define HWPIX (IMG_H*IMG_W)          // 43200
#define SPB (HWPIX*64)               // 2,764,800 floats
#define NC (NB*64)                   // 524,288

#define OFF_SPACE 0
#define OFF_A     0                  // lx_in -> kg  (dead before space zero)
#define OFF_C     NC                 // vg           (dead before space zero)
#define OFF_B     SPB                // lx_out       (lives through kImg)
#define SMB       (SPB + NC)         // 3,289,088
#define OFF_AC    (SMB)
#define OFF_T     (SMB + 8192)
#define OFF_ZERO  (SMB + 16384)      // VSUM 64 | LXSUM 64 | STATS 16 | CNT 4 | pad
#define OFF_VSUM  (OFF_ZERO)
#define OFF_LXSUM (OFF_ZERO + 64)
#define OFF_STATS (OFF_ZERO + 128)
#define OFF_CNT   (OFF_ZERO + 144)   // int[4]: per-array barrier cnt x3, global cnt
#define ZERO_CNT  160
#define OFF_SEL   (SMB + 16544)      // 3*16*64
#define OFF_CG    (SMB + 19616)      // 64
#define OFF_W1    (SMB + 19680)      // 192
#define OFF_EDGEV (SMB + 19872)      // 16*64
#define OFF_EDGEF (SMB + 20896)      // 16*64
#define OFF_BARYP (SMB + 21920)      // 3*16*64 block bary partials
#define OFF_PACK  (SMB + 24992)      // ull[3][2][16] packed argmax partials (192 floats)
#define WS_FLOATS (SMB + 25184)      // ~13.26 MB

__device__ __forceinline__ float bf2f(u16 u){
  union { unsigned int i; float f; } w; w.i = ((unsigned int)u) << 16; return w.f;
}
__device__ __forceinline__ u16 f2bf(float f){
  union { unsigned int i; float f; } w; w.f = f;
  unsigned int x = w.i;
  x += 0x7fffu + ((x >> 16) & 1u);   // RNE
  return (u16)(x >> 16);
}
__device__ __forceinline__ bool isbf(const void* ev){
  unsigned w3 = ((const unsigned*)ev)[3];
  return !(w3 == 0x3F800000u || w3 == 0xBF800000u);
}
__device__ __forceinline__ float ld(const void* p, int i, bool bf){
  return bf ? bf2f(((const u16*)p)[i]) : ((const float*)p)[i];
}
__device__ __forceinline__ void stout(void* o, long i, float v, bool bf){
  if (bf) ((u16*)o)[i] = f2bf(v); else ((float*)o)[i] = v;
}
__device__ __forceinline__ float waveSum(float v){
#pragma unroll
  for (int m = 1; m < 64; m <<= 1) v += __shfl_xor(v, m, 64);
  return v;
}
__device__ __forceinline__ ull waveMaxU64(ull v){
#pragma unroll
  for (int m = 1; m < 64; m <<= 1){
    ull o = (ull)__shfl_xor((long long)v, m, 64);
    if (o > v) v = o;
  }
  return v;
}
// pack: dist (>=0) in high 32, ~idx low 32 -> max == (max dist, min idx on tie)
__device__ __forceinline__ ull packDI(float d, int n){
  return ((ull)__float_as_uint(d) << 32) | (ull)(0xFFFFFFFFu - (unsigned)n);
}
__device__ __forceinline__ int unpackI(ull p){
  return (int)(0xFFFFFFFFu - (unsigned)(p & 0xFFFFFFFFull));
}

__global__ void kZeroSmall(float* __restrict__ ws){
  if (threadIdx.x < ZERO_CNT) ws[OFF_ZERO + threadIdx.x] = 0.f;
}
__global__ void kZeroSpace(float* __restrict__ ws){
  float4 z = make_float4(0.f, 0.f, 0.f, 0.f);
  ((float4*)(ws + OFF_SPACE))[blockIdx.x*256 + threadIdx.x] = z;
}

// ---- kW: wq1 = Wq@Wsa1, wk1 = Wk@Wsa1, wpe1 = Wpe@Wsa1 (once)
__global__ void kW(const void* __restrict__ ev, const void* __restrict__ Wq,
                   const void* __restrict__ Wk, const void* __restrict__ Wpe,
                   const void* __restrict__ w1, float* __restrict__ ws){
  const bool bf = isbf(ev);
  const int lane = threadIdx.x;  // 64
  float s1 = 0.f, s2 = 0.f;
  for (int c = 0; c < 64; c++){
    float wc = ld(w1, c, bf);
    s1 += ld(Wq, lane*64 + c, bf) * wc;
    s2 += ld(Wk, lane*64 + c, bf) * wc;
  }
  ws[OFF_W1 + lane] = s1;
  ws[OFF_W1 + 64 + lane] = s2;
  if (lane < 4){
    float s3 = 0.f;
    for (int c = 0; c < 64; c++) s3 += ld(Wpe, lane*64 + c, bf) * ld(w1, c, bf);
    ws[OFF_W1 + 128 + lane] = s3;
  }
}

// ---- kA: per row lx_in, scalars ac,t; Vsum atomic; edge v/f
__global__ void __launch_bounds__(256) kA(const void* __restrict__ ev,
    const void* __restrict__ Wm, const void* __restrict__ Wpe,
    const void* __restrict__ Wv, float* __restrict__ ws, int b){
  const bool bf = isbf(ev);
  const int lane = threadIdx.x & 63, w = threadIdx.x >> 6;
  const float wq1 = ws[OFF_W1 + lane];
  const float wk1 = ws[OFF_W1 + 64 + lane];
  const float wp10 = ws[OFF_W1+128], wp11 = ws[OFF_W1+129],
              wp12 = ws[OFF_W1+130], wp13 = ws[OFF_W1+131];
  float wmc[4], wpc[4], wvc[64];
#pragma unroll
  for (int j = 0; j < 4; j++){ wmc[j] = ld(Wm, j*64+lane, bf); wpc[j] = ld(Wpe, j*64+lane, bf); }
#pragma unroll
  for (int cn = 0; cn < 64; cn++) wvc[cn] = ld(Wv, cn*64+lane, bf);
  float vsum = 0.f;
  for (int i = 0; i < 32; i++){
    const int n = blockIdx.x*128 + w + 4*i;
    const int e4 = (b*NB + n)*4;
    float e0 = ld(ev, e4+0, bf), e1 = ld(ev, e4+1, bf),
          e2 = ld(ev, e4+2, bf), e3 = ld(ev, e4+3, bf);
    float lx = e0*wmc[0] + e1*wmc[1] + e2*wmc[2] + e3*wmc[3];
    float v = 0.f;
#pragma unroll
    for (int cn = 0; cn < 64; cn++) v += __shfl(lx, cn, 64) * wvc[cn];
    float epe = e0*wp10 + e1*wp11 + e2*wp12 + e3*wp13;
    float acv = waveSum(lx * wq1) + epe;
    float tv  = waveSum(lx * wk1) + epe;
    ws[OFF_A + n*64 + lane] = lx;
    if (lane == 0){ ws[OFF_AC + n] = acv; ws[OFF_T + n] = tv; }
    if (n < 8 || n >= NB-8){
      int e = (n < 8) ? n : (n - (NB-16));
      float f = e0*wpc[0] + e1*wpc[1] + e2*wpc[2] + e3*wpc[3];
      ws[OFF_EDGEV + e*64 + lane] = v;
      ws[OFF_EDGEF + e*64 + lane] = f;
    }
    vsum += v;
  }
  atomicAdd(&ws[OFF_VSUM + lane], vsum);
}

// ---- kC: S built from edges (kB folded); softmax; lx_out; kg/vg (3-pass, regs)
__global__ void __launch_bounds__(256) kC(const void* __restrict__ ev,
    const void* __restrict__ Wsa2, const void* __restrict__ gWk,
    const void* __restrict__ gWv, float* __restrict__ ws){
  const bool bf = isbf(ev);
  __shared__ float S_lds[1024];
  const int tid = threadIdx.x, lane = tid & 63, w = tid >> 6;
  for (int idx = tid; idx < 1024; idx += 256){
    int m = idx >> 6, c = idx & 63, d = m - 8;
    float sv = 0.f, sf = 0.f;
    if (d < 0){
      for (int e = 16 + d; e < 16; e++){ sv += ws[OFF_EDGEV+e*64+c]; sf += ws[OFF_EDGEF+e*64+c]; }
    } else {
      for (int e = 0; e < d; e++){ sv += ws[OFF_EDGEV+e*64+c]; sf += ws[OFF_EDGEF+e*64+c]; }
    }
    S_lds[idx] = ws[OFF_VSUM + c] - sv + sf;
  }
  __syncthreads();
  float wcol[64];
#pragma unroll
  for (int cn = 0; cn < 64; cn++) wcol[cn] = ld(Wsa2, cn*64 + lane, bf);
  float lxoR[32];
  float lxsum = 0.f;
#pragma unroll
  for (int i = 0; i < 32; i++){
    const int n = blockIdx.x*128 + w + 4*i;
    float lx  = ws[OFF_A + n*64 + lane];
    float acn = ws[OFF_AC + n];
    const int m = lane & 15;
    const int j = n + m - 8;
    float tv = (j >= 0 && j < NB) ? ws[OFF_T + j] : 0.f;
    float logit = acn - tv;
    float mx = logit;
#pragma unroll
    for (int k = 1; k < 16; k <<= 1) mx = fmaxf(mx, __shfl_xor(mx, k, 64));
    float ex = expf(logit - mx);
    float sm = ex;
#pragma unroll
    for (int k = 1; k < 16; k <<= 1) sm += __shfl_xor(sm, k, 64);
    float sig = ex / sm;
    float pat = 0.f;
#pragma unroll
    for (int mm = 0; mm < 16; mm++) pat += __shfl(sig, mm, 64) * S_lds[mm*64 + lane];
    float sa = 0.f;
#pragma unroll
    for (int cn = 0; cn < 64; cn++) sa += __shfl(pat, cn, 64) * wcol[cn];
    float lxo = lx + sa;
    lxoR[i] = lxo;
    ws[OFF_B + n*64 + lane] = lxo;
    lxsum += lxo;
  }
  atomicAdd(&ws[OFF_LXSUM + lane], lxsum);
#pragma unroll
  for (int cn = 0; cn < 64; cn++) wcol[cn] = ld(gWk, cn*64 + lane, bf);
#pragma unroll
  for (int i = 0; i < 32; i++){
    const int n = blockIdx.x*128 + w + 4*i;
    float kg = 0.f;
#pragma unroll
    for (int cn = 0; cn < 64; cn++) kg += __shfl(lxoR[i], cn, 64) * wcol[cn];
    ws[OFF_A + n*64 + lane] = kg;
  }
#pragma unroll
  for (int cn = 0; cn < 64; cn++) wcol[cn] = ld(gWv, cn*64 + lane, bf);
#pragma unroll
  for (int i = 0; i < 32; i++){
    const int n = blockIdx.x*128 + w + 4*i;
    float vg = 0.f;
#pragma unroll
    for (int cn = 0; cn < 64; cn++) vg += __shfl(lxoR[i], cn, 64) * wcol[cn];
    ws[OFF_C + n*64 + lane] = vg;
  }
}

// ---- kFPS: grid (16,3), 512 thr. One point/thread in regs; spin grid barriers.
// Tail (block 0,0): kG (per-batch gx_sa vector).
__global__ void __launch_bounds__(512) kFPS(const void* __restrict__ ev,
    const void* __restrict__ gWpe, const void* __restrict__ gWsa1,
    const void* __restrict__ gWsa2, float* __restrict__ ws){
  const int g = blockIdx.y, blk = blockIdx.x;
  const int tid = threadIdx.x, lane = tid & 63, w = tid >> 6;
  const int n = blk*512 + tid;
  const float* pts = ws + (g == 0 ? OFF_B : g == 1 ? OFF_A : OFF_C);
  int* cnt  = (int*)(ws + OFF_CNT) + g;
  int* gcnt = (int*)(ws + OFF_CNT) + 3;
  ull* pack = (ull*)(ws + OFF_PACK);

  __shared__ float bsum[64];
  __shared__ float cent[64];
  __shared__ ull   wv[8];
  __shared__ int   selS[16];
  __shared__ int   sCur;
  __shared__ float gfS[1024];
  __shared__ float betaS[16];
  __shared__ float GS[64];

  float4 P[16];
#pragma unroll
  for (int i = 0; i < 16; i++) P[i] = ((const float4*)(pts + (size_t)n*64))[i];

  int barNo = 0;

  // ---- barycenter: per-wave component sums -> LDS -> block partial -> barrier
  float myacc = 0.f;
#pragma unroll
  for (int c = 0; c < 16; c++){
    float v;
    v = waveSum(P[c].x); if (lane == 4*c+0) myacc = v;
    v = waveSum(P[c].y); if (lane == 4*c+1) myacc = v;
    v = waveSum(P[c].z); if (lane == 4*c+2) myacc = v;
    v = waveSum(P[c].w); if (lane == 4*c+3) myacc = v;
  }
  if (tid < 64) bsum[tid] = 0.f;
  __syncthreads();
  atomicAdd(&bsum[lane], myacc);
  __syncthreads();
  if (tid == 0){
    for (int c = 0; c < 64; c++) ws[OFF_BARYP + (g*16 + blk)*64 + c] = bsum[c];
    barNo++; __threadfence(); atomicAdd(cnt, 1);
    while (__hip_atomic_load(cnt, __ATOMIC_RELAXED, __HIP_MEMORY_SCOPE_AGENT) < 16*barNo)
      __builtin_amdgcn_s_sleep(4);
    __threadfence();
  }
  __syncthreads();
  if (tid < 64){
    float s = 0.f;
    for (int b2 = 0; b2 < 16; b2++) s += ws[OFF_BARYP + (g*16 + b2)*64 + tid];
    cent[tid] = s * (1.0f/NB);
  }
  __syncthreads();

  // ---- farthest0 = argmax dist-to-bary (no md update)
  const float4* cv = (const float4*)cent;
  float d0 = 0.f;
#pragma unroll
  for (int i = 0; i < 16; i++){
    float4 c = cv[i];
    float dx = P[i].x-c.x, dy = P[i].y-c.y, dz = P[i].z-c.z, dw = P[i].w-c.w;
    d0 += dx*dx; d0 += dy*dy; d0 += dz*dz; d0 += dw*dw;
  }
  {
    ull pk = waveMaxU64(packDI(d0, n));
    if (lane == 0) wv[w] = pk;
    __syncthreads();
    if (tid == 0){
      ull best = wv[0];
      for (int q = 1; q < 8; q++) if (wv[q] > best) best = wv[q];
      pack[(g*2 + 0)*16 + blk] = best;          // parity slot 0
      barNo++; __threadfence(); atomicAdd(cnt, 1);
      while (__hip_atomic_load(cnt, __ATOMIC_RELAXED, __HIP_MEMORY_SCOPE_AGENT) < 16*barNo)
        __builtin_amdgcn_s_sleep(4);
      __threadfence();
      ull gb = 0;
      for (int b2 = 0; b2 < 16; b2++){
        ull o = __hip_atomic_load(&pack[(g*2+0)*16 + b2], __ATOMIC_RELAXED, __HIP_MEMORY_SCOPE_AGENT);
        if (o > gb) gb = o;
      }
      sCur = unpackI(gb);
    }
    __syncthreads();
  }
  int cur = sCur;

  // ---- 16 FPS iterations; parity = (it+1)&1 so it0 uses slot 1 (no clash w/ far0)
  float md = 1e10f;
  for (int it = 0; it < 16; it++){
    if (tid == 0) selS[it] = cur;
    if (tid < 16) ((float4*)cent)[tid] = ((const float4*)(pts + (size_t)cur*64))[tid];
    __syncthreads();
    float d = 0.f;
#pragma unroll
    for (int i = 0; i < 16; i++){
      float4 c = cv[i];
      float dx = P[i].x-c.x, dy = P[i].y-c.y, dz = P[i].z-c.z, dw = P[i].w-c.w;
      d += dx*dx; d += dy*dy; d += dz*dz; d += dw*dw;
    }
    md = fminf(md, d);
    ull pk = waveMaxU64(packDI(md, n));
    if (lane == 0) wv[w] = pk;
    __syncthreads();
    const int par = (it + 1) & 1;
    if (tid == 0){
      ull best = wv[0];
      for (int q = 1; q < 8; q++) if (wv[q] > best) best = wv[q];
      pack[(g*2 + par)*16 + blk] = best;
      barNo++; __threadfence(); atomicAdd(cnt, 1);
      while (__hip_atomic_load(cnt, __ATOMIC_RELAXED, __HIP_MEMORY_SCOPE_AGENT) < 16*barNo)
        __builtin_amdgcn_s_sleep(4);
      __threadfence();
      ull gb = 0;
      for (int b2 = 0; b2 < 16; b2++){
        ull o = __hip_atomic_load(&pack[(g*2+par)*16 + b2], __ATOMIC_RELAXED, __HIP_MEMORY_SCOPE_AGENT);
        if (o > gb) gb = o;
      }
      sCur = unpackI(gb);
    }
    __syncthreads();
    cur = sCur;
  }

  // ---- leader (blk 0): sort sel asc, gather 16x64 into OFF_SEL
  if (blk == 0){
    if (tid == 0){
      for (int i = 1; i < 16; i++){
        int key = selS[i]; int j = i - 1;
        while (j >= 0 && selS[j] > key){ selS[j+1] = selS[j]; j--; }
        selS[j+1] = key;
      }
    }
    __syncthreads();
    for (int idx = tid; idx < 1024; idx += 512)
      ws[OFF_SEL + g*1024 + idx] = pts[(size_t)selS[idx >> 6]*64 + (idx & 63)];
    __threadfence();
  }
  __syncthreads();
  if (tid == 0) atomicAdd(gcnt, 1);
  if (g != 0 || blk != 0) return;

  // ---- block (0,0): wait all 48, then kG tail
  if (tid == 0){
    while (__hip_atomic_load(gcnt, __ATOMIC_RELAXED, __HIP_MEMORY_SCOPE_AGENT) < 48)
      __builtin_amdgcn_s_sleep(4);
    __threadfence();
  }
  __syncthreads();

  const bool bf = isbf(ev);
  if (tid < 64){
    const float gw1 = ld(gWsa1, tid, bf);
    float wpec[64];
#pragma unroll
    for (int cn = 0; cn < 64; cn++) wpec[cn] = ld(gWpe, cn*64 + tid, bf);
    float lxs = ws[OFF_LXSUM + tid];
    float G = 0.f;
#pragma unroll
    for (int cn = 0; cn < 64; cn++) G += __shfl(lxs, cn, 64) * wpec[cn];
    GS[tid] = G;
    const float* selp = ws + OFF_SEL;
    for (int m = 0; m < 16; m++){
      float plx = selp[m*64 + tid];
      float g2 = 0.f;
#pragma unroll
      for (int cn = 0; cn < 64; cn++) g2 += __shfl(plx, cn, 64) * wpec[cn];
      gfS[m*64 + tid] = g2;
      float pkv = selp[1024 + m*64 + tid];
      float part = waveSum((pkv + g2) * gw1);
      if (tid == 0) betaS[m] = part;
    }
  }
  __syncthreads();
  if (tid < 64){
    float mx = -1e30f;
    for (int m = 0; m < 16; m++) mx = fmaxf(mx, -betaS[m]);
    float ssum = 0.f;
    for (int m = 0; m < 16; m++) ssum += expf(-betaS[m] - mx);
    float A = 0.f;
    for (int m = 0; m < 16; m++){
      float sg = expf(-betaS[m] - mx) / ssum;
      float pv = ws[OFF_SEL + 2048 + m*64 + tid];
      float Sg = 8192.0f * (pv - gfS[m*64 + tid]) + GS[tid];
      A += sg * Sg;
    }
    float cg = 0.f;
#pragma unroll
    for (int cn = 0; cn < 64; cn++) cg += __shfl(A, cn, 64) * ld(gWsa2, cn*64 + tid, bf);
    ws[OFF_CG + tid] = cg;
  }
}

// ---- kImg: LN + exact GELU + scatter-add (index clamped)
__global__ void __launch_bounds__(256) kImg(const void* __restrict__ ev,
    const void* __restrict__ lnw, const void* __restrict__ lnb,
    float* __restrict__ ws, int b){
  const bool bf = isbf(ev);
  const int lane = threadIdx.x & 63, w = threadIdx.x >> 6;
  const float cg = ws[OFF_CG + lane];
  const float lw = ld(lnw, lane, bf), lb = ld(lnb, lane, bf);
  float* space = ws + OFF_SPACE;
  for (int i = 0; i < 32; i++){
    const int n = blockIdx.x*128 + w + 4*i;
    float x = ws[OFF_B + n*64 + lane] + cg;
    float mu = waveSum(x) * (1.0f/64.0f);
    float dv = x - mu;
    float var = waveSum(dv*dv) * (1.0f/64.0f);
    float xn = dv / sqrtf(var + 1e-5f);
    float y = xn * lw + lb;
    float h = 0.5f * y * (1.0f + erff(y * 0.70710678118654752f));
    const int e4 = (b*NB + n)*4;
    float exf = ld(ev, e4+0, bf), eyf = ld(ev, e4+1, bf), epf = ld(ev, e4+3, bf);
    int xi = (int)floorf(exf), yi = (int)floorf(eyf);
    int flat = yi*IMG_W + xi;
    flat = max(0, min(HWPIX-1, flat));
    atomicAdd(space + flat*64 + lane, epf * h);
  }
}

__global__ void __launch_bounds__(256) kStat1(float* __restrict__ ws){
  const float* sp = ws + OFF_SPACE;
  float cnt = 0.f, sum = 0.f;
  for (unsigned i = blockIdx.x*256u + threadIdx.x; i < SPB; i += gridDim.x*256u){
    float x = sp[i];
    if (x != 0.f){ cnt += 1.f; sum += x; }
  }
  cnt = waveSum(cnt); sum = waveSum(sum);
  __shared__ float rc[4], rs[4];
  const int lane = threadIdx.x & 63, w = threadIdx.x >> 6;
  if (lane == 0){ rc[w] = cnt; rs[w] = sum; }
  __syncthreads();
  if (threadIdx.x == 0){
    atomicAdd(&ws[OFF_STATS + 0], rc[0]+rc[1]+rc[2]+rc[3]);
    atomicAdd(&ws[OFF_STATS + 1], rs[0]+rs[1]+rs[2]+rs[3]);
  }
}

__global__ void __launch_bounds__(256) kStat2(float* __restrict__ ws){
  const float cnt = ws[OFF_STATS + 0];
  const float sum = ws[OFF_STATS + 1];
  const float mean = sum / fmaxf(cnt, 1.f);
  const float* sp = ws + OFF_SPACE;
  float m2 = 0.f;
  for (unsigned i = blockIdx.x*256u + threadIdx.x; i < SPB; i += gridDim.x*256u){
    float x = sp[i];
    if (x != 0.f){ float d = x - mean; m2 += d*d; }
  }
  m2 = waveSum(m2);
  __shared__ float rm[4];
  const int lane = threadIdx.x & 63, w = threadIdx.x >> 6;
  if (lane == 0) rm[w] = m2;
  __syncthreads();
  if (threadIdx.x == 0) atomicAdd(&ws[OFF_STATS + 2], rm[0]+rm[1]+rm[2]+rm[3]);
}

__global__ void __launch_bounds__(256) kOut(const void* __restrict__ ev,
    const float* __restrict__ ws, void* __restrict__ out, int b){
  const bool bf = isbf(ev);
  const int c = blockIdx.y;
  const int hw = blockIdx.x*256 + threadIdx.x;
  if (hw >= HWPIX) return;
  const float cnt = ws[OFF_STATS + 0];
  const float sum = ws[OFF_STATS + 1];
  const float m2  = ws[OFF_STATS + 2];
  const float mean = sum / fmaxf(cnt, 1.f);
  const float var  = m2 / fmaxf(cnt - 1.f, 1.f);
  const float stdv = sqrtf(var);
  float x = ws[OFF_SPACE + hw*64 + c];
  float centered = (x != 0.f) ? (x - mean) : x;
  float normed = (stdv > 0.f) ? (centered / stdv) : centered;
  float o = (cnt > 0.f) ? normed : x;
  stout(out, (long)(b*64 + c)*HWPIX + hw, o, bf);
}

extern "C" void kernel_launch(void* const* d_in, const int* in_sizes, int n_in,
                              void* d_out, int out_size, void* d_ws, size_t ws_size,
                              hipStream_t stream){
  (void)in_sizes; (void)n_in; (void)out_size; (void)ws_size;
  const void* ev     = d_in[0];
  const void* Wm     = d_in[1];
  const void* Wpe    = d_in[2];
  const void* lnw    = d_in[3];
  const void* lnb    = d_in[4];
  const void* lxWq   = d_in[5];
  const void* lxWk   = d_in[6];
  const void* lxWv   = d_in[7];
  const void* lxWsa1 = d_in[8];
  const void* lxWsa2 = d_in[9];
  // d_in[10] = gx_Wq : unused (cancels in n-independent softmax)
  const void* gxWk   = d_in[11];
  const void* gxWv   = d_in[12];
  const void* gxWpe  = d_in[13];
  const void* gxWsa1 = d_in[14];
  const void* gxWsa2 = d_in[15];
  float* ws = (float*)d_ws;

  kW<<<1, 64, 0, stream>>>(ev, lxWq, lxWk, Wpe, lxWsa1, ws);
  for (int b = 0; b < NBATCH; b++){
    kZeroSmall<<<1, 256, 0, stream>>>(ws);
    kA<<<64, 256, 0, stream>>>(ev, Wm, Wpe, lxWv, ws, b);
    kC<<<64, 256, 0, stream>>>(ev, lxWsa2, gxWk, gxWv, ws);
    kFPS<<<dim3(16, 3), 512, 0, stream>>>(ev, gxWpe, gxWsa1, gxWsa2, ws);
    kZeroSpace<<<SPB/4/256, 256, 0, stream>>>(ws);
    kImg<<<64, 256, 0, stream>>>(ev, lnw, lnb, ws, b);
    kStat1<<<256, 256, 0, stream>>>(ws);
    kStat2<<<256, 256, 0, stream>>>(ws);
    kOut<<<dim3((HWPIX+255)/256, 64), 256, 0, stream>>>(ev, ws, d_out, b);
  }
}

// Round 5
// 891.053 us; speedup vs baseline: 4.5375x; 1.1605x over previous
//
#include <hip/hip_runtime.h>

// EventTransformer on MI355X. B=2, N=8192, C=CN=64, M=16, H=180, W=240.
// fp32 internal in d_ws (~13.3 MB, batches sequential). I/O dtype (fp32/bf16)
// runtime-detected from events word 3 (p0 == +-1.0f exactly iff fp32).
//
// R5: kA/kC/kImg widened 64->512 blocks (latency-bound at 1 wave/SIMD before:
// VALUBusy 2%, Occ 2.9%). kB reinstated (S built once). kOut LDS-transpose.

typedef unsigned short u16;
typedef unsigned long long ull;

#define NB 8192
#define NBATCH 2
#define IMG_H 180
#define IMG_W 240
#define HWPIX (IMG_H*IMG_W)          // 43200
#define SPB (HWPIX*64)               // 2,764,800 floats
#define NC (NB*64)                   // 524,288

#define OFF_SPACE 0
#define OFF_A     0                  // lx_in -> kg  (dead before space zero)
#define OFF_C     NC                 // vg           (dead before space zero)
#define OFF_B     SPB                // lx_out       (lives through kImg)
#define SMB       (SPB + NC)         // 3,289,088
#define OFF_AC    (SMB)
#define OFF_T     (SMB + 8192)
#define OFF_ZERO  (SMB + 16384)      // VSUM 64 | LXSUM 64 | STATS 16 | CNT 4 | pad
#define OFF_VSUM  (OFF_ZERO)
#define OFF_LXSUM (OFF_ZERO + 64)
#define OFF_STATS (OFF_ZERO + 128)
#define OFF_CNT   (OFF_ZERO + 144)   // int[4]: per-array barrier cnt x3, global cnt
#define ZERO_CNT  160
#define OFF_SEL   (SMB + 16544)      // 3*16*64
#define OFF_CG    (SMB + 19616)      // 64
#define OFF_W1    (SMB + 19680)      // 192
#define OFF_EDGEV (SMB + 19872)      // 16*64
#define OFF_EDGEF (SMB + 20896)      // 16*64
#define OFF_BARYP (SMB + 21920)      // 3*16*64
#define OFF_PACK  (SMB + 24992)      // ull[3][2][16] (192 floats)
#define OFF_S     (SMB + 25184)      // 16*64
#define WS_FLOATS (SMB + 26208)      // ~13.26 MB

__device__ __forceinline__ float bf2f(u16 u){
  union { unsigned int i; float f; } w; w.i = ((unsigned int)u) << 16; return w.f;
}
__device__ __forceinline__ u16 f2bf(float f){
  union { unsigned int i; float f; } w; w.f = f;
  unsigned int x = w.i;
  x += 0x7fffu + ((x >> 16) & 1u);   // RNE
  return (u16)(x >> 16);
}
__device__ __forceinline__ bool isbf(const void* ev){
  unsigned w3 = ((const unsigned*)ev)[3];
  return !(w3 == 0x3F800000u || w3 == 0xBF800000u);
}
__device__ __forceinline__ float ld(const void* p, int i, bool bf){
  return bf ? bf2f(((const u16*)p)[i]) : ((const float*)p)[i];
}
__device__ __forceinline__ void stout(void* o, long i, float v, bool bf){
  if (bf) ((u16*)o)[i] = f2bf(v); else ((float*)o)[i] = v;
}
__device__ __forceinline__ float waveSum(float v){
#pragma unroll
  for (int m = 1; m < 64; m <<= 1) v += __shfl_xor(v, m, 64);
  return v;
}
__device__ __forceinline__ ull waveMaxU64(ull v){
#pragma unroll
  for (int m = 1; m < 64; m <<= 1){
    ull o = (ull)__shfl_xor((long long)v, m, 64);
    if (o > v) v = o;
  }
  return v;
}
__device__ __forceinline__ ull packDI(float d, int n){
  return ((ull)__float_as_uint(d) << 32) | (ull)(0xFFFFFFFFu - (unsigned)n);
}
__device__ __forceinline__ int unpackI(ull p){
  return (int)(0xFFFFFFFFu - (unsigned)(p & 0xFFFFFFFFull));
}

__global__ void kZeroSmall(float* __restrict__ ws){
  if (threadIdx.x < ZERO_CNT) ws[OFF_ZERO + threadIdx.x] = 0.f;
}
__global__ void kZeroSpace(float* __restrict__ ws){
  float4 z = make_float4(0.f, 0.f, 0.f, 0.f);
  ((float4*)(ws + OFF_SPACE))[blockIdx.x*256 + threadIdx.x] = z;
}

// ---- kW: wq1 = Wq@Wsa1, wk1 = Wk@Wsa1, wpe1 = Wpe@Wsa1 (once)
__global__ void kW(const void* __restrict__ ev, const void* __restrict__ Wq,
                   const void* __restrict__ Wk, const void* __restrict__ Wpe,
                   const void* __restrict__ w1, float* __restrict__ ws){
  const bool bf = isbf(ev);
  const int lane = threadIdx.x;  // 64
  float s1 = 0.f, s2 = 0.f;
  for (int c = 0; c < 64; c++){
    float wc = ld(w1, c, bf);
    s1 += ld(Wq, lane*64 + c, bf) * wc;
    s2 += ld(Wk, lane*64 + c, bf) * wc;
  }
  ws[OFF_W1 + lane] = s1;
  ws[OFF_W1 + 64 + lane] = s2;
  if (lane < 4){
    float s3 = 0.f;
    for (int c = 0; c < 64; c++) s3 += ld(Wpe, lane*64 + c, bf) * ld(w1, c, bf);
    ws[OFF_W1 + 128 + lane] = s3;
  }
}

// ---- kA: 512 blocks, 16 rows each (4 rows/wave)
__global__ void __launch_bounds__(256, 3) kA(const void* __restrict__ ev,
    const void* __restrict__ Wm, const void* __restrict__ Wpe,
    const void* __restrict__ Wv, float* __restrict__ ws, int b){
  const bool bf = isbf(ev);
  const int lane = threadIdx.x & 63, w = threadIdx.x >> 6;
  const float wq1 = ws[OFF_W1 + lane];
  const float wk1 = ws[OFF_W1 + 64 + lane];
  const float wp10 = ws[OFF_W1+128], wp11 = ws[OFF_W1+129],
              wp12 = ws[OFF_W1+130], wp13 = ws[OFF_W1+131];
  float wmc[4], wpc[4], wvc[64];
#pragma unroll
  for (int j = 0; j < 4; j++){ wmc[j] = ld(Wm, j*64+lane, bf); wpc[j] = ld(Wpe, j*64+lane, bf); }
#pragma unroll
  for (int cn = 0; cn < 64; cn++) wvc[cn] = ld(Wv, cn*64+lane, bf);
  float vsum = 0.f;
#pragma unroll
  for (int i = 0; i < 4; i++){
    const int n = blockIdx.x*16 + w + 4*i;
    const int e4 = (b*NB + n)*4;
    float e0 = ld(ev, e4+0, bf), e1 = ld(ev, e4+1, bf),
          e2 = ld(ev, e4+2, bf), e3 = ld(ev, e4+3, bf);
    float lx = e0*wmc[0] + e1*wmc[1] + e2*wmc[2] + e3*wmc[3];
    float v = 0.f;
#pragma unroll
    for (int cn = 0; cn < 64; cn++) v += __shfl(lx, cn, 64) * wvc[cn];
    float epe = e0*wp10 + e1*wp11 + e2*wp12 + e3*wp13;
    float acv = waveSum(lx * wq1) + epe;
    float tv  = waveSum(lx * wk1) + epe;
    ws[OFF_A + n*64 + lane] = lx;
    if (lane == 0){ ws[OFF_AC + n] = acv; ws[OFF_T + n] = tv; }
    if (n < 8 || n >= NB-8){
      int e = (n < 8) ? n : (n - (NB-16));
      float f = e0*wpc[0] + e1*wpc[1] + e2*wpc[2] + e3*wpc[3];
      ws[OFF_EDGEV + e*64 + lane] = v;
      ws[OFF_EDGEF + e*64 + lane] = f;
    }
    vsum += v;
  }
  atomicAdd(&ws[OFF_VSUM + lane], vsum);
}

// ---- kB: S[m,c] = Vsum[c] - excl_v(m) + excl_f(m)
__global__ void __launch_bounds__(64) kB(float* __restrict__ ws){
  const int m = blockIdx.x, lane = threadIdx.x;
  const int d = m - 8;
  float sv = 0.f, sf = 0.f;
  if (d < 0){
    for (int e = 16 + d; e < 16; e++){ sv += ws[OFF_EDGEV+e*64+lane]; sf += ws[OFF_EDGEF+e*64+lane]; }
  } else {
    for (int e = 0; e < d; e++){ sv += ws[OFF_EDGEV+e*64+lane]; sf += ws[OFF_EDGEF+e*64+lane]; }
  }
  ws[OFF_S + m*64 + lane] = ws[OFF_VSUM + lane] - sv + sf;
}

// ---- kC: 512 blocks, 16 rows each; softmax; lx_out; kg/vg (3-pass regs)
__global__ void __launch_bounds__(256, 3) kC(const void* __restrict__ ev,
    const void* __restrict__ Wsa2, const void* __restrict__ gWk,
    const void* __restrict__ gWv, float* __restrict__ ws){
  const bool bf = isbf(ev);
  __shared__ float S_lds[1024];
  const int tid = threadIdx.x, lane = tid & 63, w = tid >> 6;
  for (int i = tid; i < 1024; i += 256) S_lds[i] = ws[OFF_S + i];
  __syncthreads();
  float wcol[64];
#pragma unroll
  for (int cn = 0; cn < 64; cn++) wcol[cn] = ld(Wsa2, cn*64 + lane, bf);
  float lxoR[4];
  float lxsum = 0.f;
#pragma unroll
  for (int i = 0; i < 4; i++){
    const int n = blockIdx.x*16 + w + 4*i;
    float lx  = ws[OFF_A + n*64 + lane];
    float acn = ws[OFF_AC + n];
    const int m = lane & 15;
    const int j = n + m - 8;
    float tv = (j >= 0 && j < NB) ? ws[OFF_T + j] : 0.f;
    float logit = acn - tv;
    float mx = logit;
#pragma unroll
    for (int k = 1; k < 16; k <<= 1) mx = fmaxf(mx, __shfl_xor(mx, k, 64));
    float ex = expf(logit - mx);
    float sm = ex;
#pragma unroll
    for (int k = 1; k < 16; k <<= 1) sm += __shfl_xor(sm, k, 64);
    float sig = ex / sm;
    float pat = 0.f;
#pragma unroll
    for (int mm = 0; mm < 16; mm++) pat += __shfl(sig, mm, 64) * S_lds[mm*64 + lane];
    float sa = 0.f;
#pragma unroll
    for (int cn = 0; cn < 64; cn++) sa += __shfl(pat, cn, 64) * wcol[cn];
    float lxo = lx + sa;
    lxoR[i] = lxo;
    ws[OFF_B + n*64 + lane] = lxo;
    lxsum += lxo;
  }
  atomicAdd(&ws[OFF_LXSUM + lane], lxsum);
#pragma unroll
  for (int cn = 0; cn < 64; cn++) wcol[cn] = ld(gWk, cn*64 + lane, bf);
#pragma unroll
  for (int i = 0; i < 4; i++){
    const int n = blockIdx.x*16 + w + 4*i;
    float kg = 0.f;
#pragma unroll
    for (int cn = 0; cn < 64; cn++) kg += __shfl(lxoR[i], cn, 64) * wcol[cn];
    ws[OFF_A + n*64 + lane] = kg;
  }
#pragma unroll
  for (int cn = 0; cn < 64; cn++) wcol[cn] = ld(gWv, cn*64 + lane, bf);
#pragma unroll
  for (int i = 0; i < 4; i++){
    const int n = blockIdx.x*16 + w + 4*i;
    float vg = 0.f;
#pragma unroll
    for (int cn = 0; cn < 64; cn++) vg += __shfl(lxoR[i], cn, 64) * wcol[cn];
    ws[OFF_C + n*64 + lane] = vg;
  }
}

// ---- kFPS: grid (16,3), 512 thr; regs-resident points; spin grid barriers.
__global__ void __launch_bounds__(512) kFPS(const void* __restrict__ ev,
    const void* __restrict__ gWpe, const void* __restrict__ gWsa1,
    const void* __restrict__ gWsa2, float* __restrict__ ws){
  const int g = blockIdx.y, blk = blockIdx.x;
  const int tid = threadIdx.x, lane = tid & 63, w = tid >> 6;
  const int n = blk*512 + tid;
  const float* pts = ws + (g == 0 ? OFF_B : g == 1 ? OFF_A : OFF_C);
  int* cnt  = (int*)(ws + OFF_CNT) + g;
  int* gcnt = (int*)(ws + OFF_CNT) + 3;
  ull* pack = (ull*)(ws + OFF_PACK);

  __shared__ float bsum[64];
  __shared__ float cent[64];
  __shared__ ull   wv[8];
  __shared__ int   selS[16];
  __shared__ int   sCur;
  __shared__ float gfS[1024];
  __shared__ float betaS[16];
  __shared__ float GS[64];

  float4 P[16];
#pragma unroll
  for (int i = 0; i < 16; i++) P[i] = ((const float4*)(pts + (size_t)n*64))[i];

  int barNo = 0;

  float myacc = 0.f;
#pragma unroll
  for (int c = 0; c < 16; c++){
    float v;
    v = waveSum(P[c].x); if (lane == 4*c+0) myacc = v;
    v = waveSum(P[c].y); if (lane == 4*c+1) myacc = v;
    v = waveSum(P[c].z); if (lane == 4*c+2) myacc = v;
    v = waveSum(P[c].w); if (lane == 4*c+3) myacc = v;
  }
  if (tid < 64) bsum[tid] = 0.f;
  __syncthreads();
  atomicAdd(&bsum[lane], myacc);
  __syncthreads();
  if (tid == 0){
    for (int c = 0; c < 64; c++) ws[OFF_BARYP + (g*16 + blk)*64 + c] = bsum[c];
    barNo++; __threadfence(); atomicAdd(cnt, 1);
    while (__hip_atomic_load(cnt, __ATOMIC_RELAXED, __HIP_MEMORY_SCOPE_AGENT) < 16*barNo)
      __builtin_amdgcn_s_sleep(4);
    __threadfence();
  }
  __syncthreads();
  if (tid < 64){
    float s = 0.f;
    for (int b2 = 0; b2 < 16; b2++) s += ws[OFF_BARYP + (g*16 + b2)*64 + tid];
    cent[tid] = s * (1.0f/NB);
  }
  __syncthreads();

  const float4* cv = (const float4*)cent;
  float d0 = 0.f;
#pragma unroll
  for (int i = 0; i < 16; i++){
    float4 c = cv[i];
    float dx = P[i].x-c.x, dy = P[i].y-c.y, dz = P[i].z-c.z, dw = P[i].w-c.w;
    d0 += dx*dx; d0 += dy*dy; d0 += dz*dz; d0 += dw*dw;
  }
  {
    ull pk = waveMaxU64(packDI(d0, n));
    if (lane == 0) wv[w] = pk;
    __syncthreads();
    if (tid == 0){
      ull best = wv[0];
      for (int q = 1; q < 8; q++) if (wv[q] > best) best = wv[q];
      pack[(g*2 + 0)*16 + blk] = best;
      barNo++; __threadfence(); atomicAdd(cnt, 1);
      while (__hip_atomic_load(cnt, __ATOMIC_RELAXED, __HIP_MEMORY_SCOPE_AGENT) < 16*barNo)
        __builtin_amdgcn_s_sleep(4);
      __threadfence();
      ull gb = 0;
      for (int b2 = 0; b2 < 16; b2++){
        ull o = __hip_atomic_load(&pack[(g*2+0)*16 + b2], __ATOMIC_RELAXED, __HIP_MEMORY_SCOPE_AGENT);
        if (o > gb) gb = o;
      }
      sCur = unpackI(gb);
    }
    __syncthreads();
  }
  int cur = sCur;

  float md = 1e10f;
  for (int it = 0; it < 16; it++){
    if (tid == 0) selS[it] = cur;
    if (tid < 16) ((float4*)cent)[tid] = ((const float4*)(pts + (size_t)cur*64))[tid];
    __syncthreads();
    float d = 0.f;
#pragma unroll
    for (int i = 0; i < 16; i++){
      float4 c = cv[i];
      float dx = P[i].x-c.x, dy = P[i].y-c.y, dz = P[i].z-c.z, dw = P[i].w-c.w;
      d += dx*dx; d += dy*dy; d += dz*dz; d += dw*dw;
    }
    md = fminf(md, d);
    ull pk = waveMaxU64(packDI(md, n));
    if (lane == 0) wv[w] = pk;
    __syncthreads();
    const int par = (it + 1) & 1;
    if (tid == 0){
      ull best = wv[0];
      for (int q = 1; q < 8; q++) if (wv[q] > best) best = wv[q];
      pack[(g*2 + par)*16 + blk] = best;
      barNo++; __threadfence(); atomicAdd(cnt, 1);
      while (__hip_atomic_load(cnt, __ATOMIC_RELAXED, __HIP_MEMORY_SCOPE_AGENT) < 16*barNo)
        __builtin_amdgcn_s_sleep(4);
      __threadfence();
      ull gb = 0;
      for (int b2 = 0; b2 < 16; b2++){
        ull o = __hip_atomic_load(&pack[(g*2+par)*16 + b2], __ATOMIC_RELAXED, __HIP_MEMORY_SCOPE_AGENT);
        if (o > gb) gb = o;
      }
      sCur = unpackI(gb);
    }
    __syncthreads();
    cur = sCur;
  }

  if (blk == 0){
    if (tid == 0){
      for (int i = 1; i < 16; i++){
        int key = selS[i]; int j = i - 1;
        while (j >= 0 && selS[j] > key){ selS[j+1] = selS[j]; j--; }
        selS[j+1] = key;
      }
    }
    __syncthreads();
    for (int idx = tid; idx < 1024; idx += 512)
      ws[OFF_SEL + g*1024 + idx] = pts[(size_t)selS[idx >> 6]*64 + (idx & 63)];
    __threadfence();
  }
  __syncthreads();
  if (tid == 0) atomicAdd(gcnt, 1);
  if (g != 0 || blk != 0) return;

  if (tid == 0){
    while (__hip_atomic_load(gcnt, __ATOMIC_RELAXED, __HIP_MEMORY_SCOPE_AGENT) < 48)
      __builtin_amdgcn_s_sleep(4);
    __threadfence();
  }
  __syncthreads();

  const bool bf = isbf(ev);
  if (tid < 64){
    const float gw1 = ld(gWsa1, tid, bf);
    float wpec[64];
#pragma unroll
    for (int cn = 0; cn < 64; cn++) wpec[cn] = ld(gWpe, cn*64 + tid, bf);
    float lxs = ws[OFF_LXSUM + tid];
    float G = 0.f;
#pragma unroll
    for (int cn = 0; cn < 64; cn++) G += __shfl(lxs, cn, 64) * wpec[cn];
    GS[tid] = G;
    const float* selp = ws + OFF_SEL;
    for (int m = 0; m < 16; m++){
      float plx = selp[m*64 + tid];
      float g2 = 0.f;
#pragma unroll
      for (int cn = 0; cn < 64; cn++) g2 += __shfl(plx, cn, 64) * wpec[cn];
      gfS[m*64 + tid] = g2;
      float pkv = selp[1024 + m*64 + tid];
      float part = waveSum((pkv + g2) * gw1);
      if (tid == 0) betaS[m] = part;
    }
  }
  __syncthreads();
  if (tid < 64){
    float mx = -1e30f;
    for (int m = 0; m < 16; m++) mx = fmaxf(mx, -betaS[m]);
    float ssum = 0.f;
    for (int m = 0; m < 16; m++) ssum += expf(-betaS[m] - mx);
    float A = 0.f;
    for (int m = 0; m < 16; m++){
      float sg = expf(-betaS[m] - mx) / ssum;
      float pv = ws[OFF_SEL + 2048 + m*64 + tid];
      float Sg = 8192.0f * (pv - gfS[m*64 + tid]) + GS[tid];
      A += sg * Sg;
    }
    float cg = 0.f;
#pragma unroll
    for (int cn = 0; cn < 64; cn++) cg += __shfl(A, cn, 64) * ld(gWsa2, cn*64 + tid, bf);
    ws[OFF_CG + tid] = cg;
  }
}

// ---- kImg: 512 blocks, 16 rows each; LN + GELU + scatter-add
__global__ void __launch_bounds__(256, 3) kImg(const void* __restrict__ ev,
    const void* __restrict__ lnw, const void* __restrict__ lnb,
    float* __restrict__ ws, int b){
  const bool bf = isbf(ev);
  const int lane = threadIdx.x & 63, w = threadIdx.x >> 6;
  const float cg = ws[OFF_CG + lane];
  const float lw = ld(lnw, lane, bf), lb = ld(lnb, lane, bf);
  float* space = ws + OFF_SPACE;
#pragma unroll
  for (int i = 0; i < 4; i++){
    const int n = blockIdx.x*16 + w + 4*i;
    float x = ws[OFF_B + n*64 + lane] + cg;
    float mu = waveSum(x) * (1.0f/64.0f);
    float dv = x - mu;
    float var = waveSum(dv*dv) * (1.0f/64.0f);
    float xn = dv / sqrtf(var + 1e-5f);
    float y = xn * lw + lb;
    float h = 0.5f * y * (1.0f + erff(y * 0.70710678118654752f));
    const int e4 = (b*NB + n)*4;
    float exf = ld(ev, e4+0, bf), eyf = ld(ev, e4+1, bf), epf = ld(ev, e4+3, bf);
    int xi = (int)floorf(exf), yi = (int)floorf(eyf);
    int flat = yi*IMG_W + xi;
    flat = max(0, min(HWPIX-1, flat));
    atomicAdd(space + flat*64 + lane, epf * h);
  }
}

__global__ void __launch_bounds__(256) kStat1(float* __restrict__ ws){
  const float* sp = ws + OFF_SPACE;
  float cnt = 0.f, sum = 0.f;
  for (unsigned i = blockIdx.x*256u + threadIdx.x; i < SPB; i += gridDim.x*256u){
    float x = sp[i];
    if (x != 0.f){ cnt += 1.f; sum += x; }
  }
  cnt = waveSum(cnt); sum = waveSum(sum);
  __shared__ float rc[4], rs[4];
  const int lane = threadIdx.x & 63, w = threadIdx.x >> 6;
  if (lane == 0){ rc[w] = cnt; rs[w] = sum; }
  __syncthreads();
  if (threadIdx.x == 0){
    atomicAdd(&ws[OFF_STATS + 0], rc[0]+rc[1]+rc[2]+rc[3]);
    atomicAdd(&ws[OFF_STATS + 1], rs[0]+rs[1]+rs[2]+rs[3]);
  }
}

__global__ void __launch_bounds__(256) kStat2(float* __restrict__ ws){
  const float cnt = ws[OFF_STATS + 0];
  const float sum = ws[OFF_STATS + 1];
  const float mean = sum / fmaxf(cnt, 1.f);
  const float* sp = ws + OFF_SPACE;
  float m2 = 0.f;
  for (unsigned i = blockIdx.x*256u + threadIdx.x; i < SPB; i += gridDim.x*256u){
    float x = sp[i];
    if (x != 0.f){ float d = x - mean; m2 += d*d; }
  }
  m2 = waveSum(m2);
  __shared__ float rm[4];
  const int lane = threadIdx.x & 63, w = threadIdx.x >> 6;
  if (lane == 0) rm[w] = m2;
  __syncthreads();
  if (threadIdx.x == 0) atomicAdd(&ws[OFF_STATS + 2], rm[0]+rm[1]+rm[2]+rm[3]);
}

// ---- kOut: LDS-transpose 64hw x 64c tile; both sides coalesced. grid 675.
__global__ void __launch_bounds__(256) kOut(const void* __restrict__ ev,
    const float* __restrict__ ws, void* __restrict__ out, int b){
  const bool bf = isbf(ev);
  __shared__ float tile[64*64];
  const int tid = threadIdx.x;
  const int hw0 = blockIdx.x*64;
#pragma unroll
  for (int i = 0; i < 16; i++){
    int idx = tid + 256*i;
    tile[idx] = ws[OFF_SPACE + (size_t)hw0*64 + idx];
  }
  const float cnt = ws[OFF_STATS + 0];
  const float sum = ws[OFF_STATS + 1];
  const float m2  = ws[OFF_STATS + 2];
  const float mean = sum / fmaxf(cnt, 1.f);
  const float var  = m2 / fmaxf(cnt - 1.f, 1.f);
  const float stdv = sqrtf(var);
  __syncthreads();
  const int c = tid >> 2, sub = tid & 3;
#pragma unroll
  for (int j = 0; j < 16; j++){
    int hwl = sub*16 + j;
    float x = tile[hwl*64 + c];
    float centered = (x != 0.f) ? (x - mean) : x;
    float normed = (stdv > 0.f) ? (centered / stdv) : centered;
    float o = (cnt > 0.f) ? normed : x;
    stout(out, (long)(b*64 + c)*HWPIX + hw0 + hwl, o, bf);
  }
}

extern "C" void kernel_launch(void* const* d_in, const int* in_sizes, int n_in,
                              void* d_out, int out_size, void* d_ws, size_t ws_size,
                              hipStream_t stream){
  (void)in_sizes; (void)n_in; (void)out_size; (void)ws_size;
  const void* ev     = d_in[0];
  const void* Wm     = d_in[1];
  const void* Wpe    = d_in[2];
  const void* lnw    = d_in[3];
  const void* lnb    = d_in[4];
  const void* lxWq   = d_in[5];
  const void* lxWk   = d_in[6];
  const void* lxWv   = d_in[7];
  const void* lxWsa1 = d_in[8];
  const void* lxWsa2 = d_in[9];
  // d_in[10] = gx_Wq : unused (cancels in n-independent softmax)
  const void* gxWk   = d_in[11];
  const void* gxWv   = d_in[12];
  const void* gxWpe  = d_in[13];
  const void* gxWsa1 = d_in[14];
  const void* gxWsa2 = d_in[15];
  float* ws = (float*)d_ws;

  kW<<<1, 64, 0, stream>>>(ev, lxWq, lxWk, Wpe, lxWsa1, ws);
  for (int b = 0; b < NBATCH; b++){
    kZeroSmall<<<1, 256, 0, stream>>>(ws);
    kA<<<512, 256, 0, stream>>>(ev, Wm, Wpe, lxWv, ws, b);
    kB<<<16, 64, 0, stream>>>(ws);
    kC<<<512, 256, 0, stream>>>(ev, lxWsa2, gxWk, gxWv, ws);
    kFPS<<<dim3(16, 3), 512, 0, stream>>>(ev, gxWpe, gxWsa1, gxWsa2, ws);
    kZeroSpace<<<SPB/4/256, 256, 0, stream>>>(ws);
    kImg<<<512, 256, 0, stream>>>(ev, lnw, lnb, ws, b);
    kStat1<<<256, 256, 0, stream>>>(ws);
    kStat2<<<256, 256, 0, stream>>>(ws);
    kOut<<<675, 256, 0, stream>>>(ev, ws, d_out, b);
  }
}

// Round 6
// 796.964 us; speedup vs baseline: 5.0732x; 1.1181x over previous
//
#include <hip/hip_runtime.h>

// EventTransformer on MI355X. B=2, N=8192, C=CN=64, M=16, H=180, W=240.
// fp32 internal in d_ws (~13.3 MB, batches sequential). I/O dtype (fp32/bf16)
// runtime-detected from events word 3 (p0 == +-1.0f exactly iff fp32).
//
// R6: kFPS barriers restructured — bary computed analytically from LXSUM
// (linearity), argmax via single packed atomicMax (phase-monotonic, parity
// double-buffered), 8 blocks/group w/ 2 pts/thread in regs. kStat1+2 fused.

typedef unsigned short u16;
typedef unsigned long long ull;

#define NB 8192
#define NBATCH 2
#define IMG_H 180
#define IMG_W 240
#define HWPIX (IMG_H*IMG_W)          // 43200
#define SPB (HWPIX*64)               // 2,764,800 floats
#define NC (NB*64)                   // 524,288

#define OFF_SPACE 0
#define OFF_A     0                  // lx_in -> kg  (dead before space zero)
#define OFF_C     NC                 // vg           (dead before space zero)
#define OFF_B     SPB                // lx_out       (lives through kImg)
#define SMB       (SPB + NC)         // 3,289,088
#define OFF_AC    (SMB)
#define OFF_T     (SMB + 8192)
#define OFF_ZERO  (SMB + 16384)
#define OFF_VSUM  (OFF_ZERO)         // 64
#define OFF_LXSUM (OFF_ZERO + 64)    // 64
#define OFF_STATS (OFF_ZERO + 128)   // cnt,sum,sumsq,pad
#define OFF_CNT   (OFF_ZERO + 144)   // int[4]: barrier cnt x3, global cnt
#define OFF_BEST  (OFF_ZERO + 148)   // ull[3][2] = 12 floats (8B aligned)
#define ZERO_CNT  160
#define OFF_SEL   (SMB + 16544)      // 3*16*64
#define OFF_CG    (SMB + 19616)      // 64
#define OFF_W1    (SMB + 19680)      // 192
#define OFF_EDGEV (SMB + 19872)      // 16*64
#define OFF_EDGEF (SMB + 20896)      // 16*64
#define OFF_S     (SMB + 21920)      // 16*64
#define WS_FLOATS (SMB + 22944)      // ~13.25 MB

__device__ __forceinline__ float bf2f(u16 u){
  union { unsigned int i; float f; } w; w.i = ((unsigned int)u) << 16; return w.f;
}
__device__ __forceinline__ u16 f2bf(float f){
  union { unsigned int i; float f; } w; w.f = f;
  unsigned int x = w.i;
  x += 0x7fffu + ((x >> 16) & 1u);   // RNE
  return (u16)(x >> 16);
}
__device__ __forceinline__ bool isbf(const void* ev){
  unsigned w3 = ((const unsigned*)ev)[3];
  return !(w3 == 0x3F800000u || w3 == 0xBF800000u);
}
__device__ __forceinline__ float ld(const void* p, int i, bool bf){
  return bf ? bf2f(((const u16*)p)[i]) : ((const float*)p)[i];
}
__device__ __forceinline__ void stout(void* o, long i, float v, bool bf){
  if (bf) ((u16*)o)[i] = f2bf(v); else ((float*)o)[i] = v;
}
__device__ __forceinline__ float waveSum(float v){
#pragma unroll
  for (int m = 1; m < 64; m <<= 1) v += __shfl_xor(v, m, 64);
  return v;
}
__device__ __forceinline__ ull waveMaxU64(ull v){
#pragma unroll
  for (int m = 1; m < 64; m <<= 1){
    ull o = (ull)__shfl_xor((long long)v, m, 64);
    if (o > v) v = o;
  }
  return v;
}
// pack: [52:45]=phase, [44:13]=dist bits (d>=0), [12:0]=8191-idx (tie->min idx)
__device__ __forceinline__ ull packPDI(int phase, float d, int n){
  return ((ull)phase << 45) | ((ull)__float_as_uint(d) << 13) | (ull)(8191 - n);
}
__device__ __forceinline__ int unpackI(ull p){ return 8191 - (int)(p & 0x1FFFull); }

__global__ void kZeroSmall(float* __restrict__ ws){
  if (threadIdx.x < ZERO_CNT) ws[OFF_ZERO + threadIdx.x] = 0.f;
}
__global__ void kZeroSpace(float* __restrict__ ws){
  float4 z = make_float4(0.f, 0.f, 0.f, 0.f);
  ((float4*)(ws + OFF_SPACE))[blockIdx.x*256 + threadIdx.x] = z;
}

// ---- kW: wq1 = Wq@Wsa1, wk1 = Wk@Wsa1, wpe1 = Wpe@Wsa1 (once)
__global__ void kW(const void* __restrict__ ev, const void* __restrict__ Wq,
                   const void* __restrict__ Wk, const void* __restrict__ Wpe,
                   const void* __restrict__ w1, float* __restrict__ ws){
  const bool bf = isbf(ev);
  const int lane = threadIdx.x;  // 64
  float s1 = 0.f, s2 = 0.f;
  for (int c = 0; c < 64; c++){
    float wc = ld(w1, c, bf);
    s1 += ld(Wq, lane*64 + c, bf) * wc;
    s2 += ld(Wk, lane*64 + c, bf) * wc;
  }
  ws[OFF_W1 + lane] = s1;
  ws[OFF_W1 + 64 + lane] = s2;
  if (lane < 4){
    float s3 = 0.f;
    for (int c = 0; c < 64; c++) s3 += ld(Wpe, lane*64 + c, bf) * ld(w1, c, bf);
    ws[OFF_W1 + 128 + lane] = s3;
  }
}

// ---- kA: 512 blocks, 16 rows each
__global__ void __launch_bounds__(256, 3) kA(const void* __restrict__ ev,
    const void* __restrict__ Wm, const void* __restrict__ Wpe,
    const void* __restrict__ Wv, float* __restrict__ ws, int b){
  const bool bf = isbf(ev);
  const int lane = threadIdx.x & 63, w = threadIdx.x >> 6;
  const float wq1 = ws[OFF_W1 + lane];
  const float wk1 = ws[OFF_W1 + 64 + lane];
  const float wp10 = ws[OFF_W1+128], wp11 = ws[OFF_W1+129],
              wp12 = ws[OFF_W1+130], wp13 = ws[OFF_W1+131];
  float wmc[4], wpc[4], wvc[64];
#pragma unroll
  for (int j = 0; j < 4; j++){ wmc[j] = ld(Wm, j*64+lane, bf); wpc[j] = ld(Wpe, j*64+lane, bf); }
#pragma unroll
  for (int cn = 0; cn < 64; cn++) wvc[cn] = ld(Wv, cn*64+lane, bf);
  float vsum = 0.f;
#pragma unroll
  for (int i = 0; i < 4; i++){
    const int n = blockIdx.x*16 + w + 4*i;
    const int e4 = (b*NB + n)*4;
    float e0 = ld(ev, e4+0, bf), e1 = ld(ev, e4+1, bf),
          e2 = ld(ev, e4+2, bf), e3 = ld(ev, e4+3, bf);
    float lx = e0*wmc[0] + e1*wmc[1] + e2*wmc[2] + e3*wmc[3];
    float v = 0.f;
#pragma unroll
    for (int cn = 0; cn < 64; cn++) v += __shfl(lx, cn, 64) * wvc[cn];
    float epe = e0*wp10 + e1*wp11 + e2*wp12 + e3*wp13;
    float acv = waveSum(lx * wq1) + epe;
    float tv  = waveSum(lx * wk1) + epe;
    ws[OFF_A + n*64 + lane] = lx;
    if (lane == 0){ ws[OFF_AC + n] = acv; ws[OFF_T + n] = tv; }
    if (n < 8 || n >= NB-8){
      int e = (n < 8) ? n : (n - (NB-16));
      float f = e0*wpc[0] + e1*wpc[1] + e2*wpc[2] + e3*wpc[3];
      ws[OFF_EDGEV + e*64 + lane] = v;
      ws[OFF_EDGEF + e*64 + lane] = f;
    }
    vsum += v;
  }
  atomicAdd(&ws[OFF_VSUM + lane], vsum);
}

// ---- kB: S[m,c] = Vsum[c] - excl_v(m) + excl_f(m)
__global__ void __launch_bounds__(64) kB(float* __restrict__ ws){
  const int m = blockIdx.x, lane = threadIdx.x;
  const int d = m - 8;
  float sv = 0.f, sf = 0.f;
  if (d < 0){
    for (int e = 16 + d; e < 16; e++){ sv += ws[OFF_EDGEV+e*64+lane]; sf += ws[OFF_EDGEF+e*64+lane]; }
  } else {
    for (int e = 0; e < d; e++){ sv += ws[OFF_EDGEV+e*64+lane]; sf += ws[OFF_EDGEF+e*64+lane]; }
  }
  ws[OFF_S + m*64 + lane] = ws[OFF_VSUM + lane] - sv + sf;
}

// ---- kC: 512 blocks, 16 rows each; softmax; lx_out; kg/vg (3-pass regs)
__global__ void __launch_bounds__(256, 3) kC(const void* __restrict__ ev,
    const void* __restrict__ Wsa2, const void* __restrict__ gWk,
    const void* __restrict__ gWv, float* __restrict__ ws){
  const bool bf = isbf(ev);
  __shared__ float S_lds[1024];
  const int tid = threadIdx.x, lane = tid & 63, w = tid >> 6;
  for (int i = tid; i < 1024; i += 256) S_lds[i] = ws[OFF_S + i];
  __syncthreads();
  float wcol[64];
#pragma unroll
  for (int cn = 0; cn < 64; cn++) wcol[cn] = ld(Wsa2, cn*64 + lane, bf);
  float lxoR[4];
  float lxsum = 0.f;
#pragma unroll
  for (int i = 0; i < 4; i++){
    const int n = blockIdx.x*16 + w + 4*i;
    float lx  = ws[OFF_A + n*64 + lane];
    float acn = ws[OFF_AC + n];
    const int m = lane & 15;
    const int j = n + m - 8;
    float tv = (j >= 0 && j < NB) ? ws[OFF_T + j] : 0.f;
    float logit = acn - tv;
    float mx = logit;
#pragma unroll
    for (int k = 1; k < 16; k <<= 1) mx = fmaxf(mx, __shfl_xor(mx, k, 64));
    float ex = expf(logit - mx);
    float sm = ex;
#pragma unroll
    for (int k = 1; k < 16; k <<= 1) sm += __shfl_xor(sm, k, 64);
    float sig = ex / sm;
    float pat = 0.f;
#pragma unroll
    for (int mm = 0; mm < 16; mm++) pat += __shfl(sig, mm, 64) * S_lds[mm*64 + lane];
    float sa = 0.f;
#pragma unroll
    for (int cn = 0; cn < 64; cn++) sa += __shfl(pat, cn, 64) * wcol[cn];
    float lxo = lx + sa;
    lxoR[i] = lxo;
    ws[OFF_B + n*64 + lane] = lxo;
    lxsum += lxo;
  }
  atomicAdd(&ws[OFF_LXSUM + lane], lxsum);
#pragma unroll
  for (int cn = 0; cn < 64; cn++) wcol[cn] = ld(gWk, cn*64 + lane, bf);
#pragma unroll
  for (int i = 0; i < 4; i++){
    const int n = blockIdx.x*16 + w + 4*i;
    float kg = 0.f;
#pragma unroll
    for (int cn = 0; cn < 64; cn++) kg += __shfl(lxoR[i], cn, 64) * wcol[cn];
    ws[OFF_A + n*64 + lane] = kg;
  }
#pragma unroll
  for (int cn = 0; cn < 64; cn++) wcol[cn] = ld(gWv, cn*64 + lane, bf);
#pragma unroll
  for (int i = 0; i < 4; i++){
    const int n = blockIdx.x*16 + w + 4*i;
    float vg = 0.f;
#pragma unroll
    for (int cn = 0; cn < 64; cn++) vg += __shfl(lxoR[i], cn, 64) * wcol[cn];
    ws[OFF_C + n*64 + lane] = vg;
  }
}

// ---- kFPS: grid (8,3), 512 thr, 2 pts/thread in regs. Bary from LXSUM.
// Cross-block argmax: packed atomicMax (phase-prefixed), parity double-buffer.
// Tail (block 0,0): kG.
__global__ void __launch_bounds__(512) kFPS(const void* __restrict__ ev,
    const void* __restrict__ gWk, const void* __restrict__ gWv,
    const void* __restrict__ gWpe, const void* __restrict__ gWsa1,
    const void* __restrict__ gWsa2, float* __restrict__ ws){
  const int g = blockIdx.y, blk = blockIdx.x;
  const int tid = threadIdx.x, lane = tid & 63, w = tid >> 6;
  const float* pts = ws + (g == 0 ? OFF_B : g == 1 ? OFF_A : OFF_C);
  int* cnt  = (int*)(ws + OFF_CNT) + g;
  int* gcnt = (int*)(ws + OFF_CNT) + 3;
  ull* best = (ull*)(ws + OFF_BEST);   // [g][parity]

  __shared__ float cent[64];
  __shared__ ull   wv[8];
  __shared__ int   selS[16];
  __shared__ int   sCur;
  __shared__ float gfS[1024];
  __shared__ float betaS[16];
  __shared__ float GS[64];

  const int n0 = blk*1024 + tid;       // +0 and +512
  float4 P[2][16];
#pragma unroll
  for (int j = 0; j < 2; j++)
#pragma unroll
    for (int i = 0; i < 16; i++)
      P[j][i] = ((const float4*)(pts + (size_t)(n0 + j*512)*64))[i];

  // bary analytically: g0 = LXSUM/N; g1 = (LXSUM/N)@gWk; g2 = (LXSUM/N)@gWv
  const bool bf = isbf(ev);
  if (tid < 64){
    float lxs = ws[OFF_LXSUM + tid];
    float c;
    if (g == 0) c = lxs * (1.0f/NB);
    else {
      const void* W = (g == 1) ? gWk : gWv;
      float s = 0.f;
#pragma unroll
      for (int j = 0; j < 64; j++) s += __shfl(lxs, j, 64) * ld(W, j*64 + tid, bf);
      c = s * (1.0f/NB);
    }
    cent[tid] = c;
  }
  __syncthreads();

  int phase = 1;
  const float4* cv = (const float4*)cent;
  float md[2] = {1e10f, 1e10f};
  ull myp;
  { // farthest0 (no md update)
    float dd[2];
#pragma unroll
    for (int j = 0; j < 2; j++){
      float d = 0.f;
#pragma unroll
      for (int i = 0; i < 16; i++){
        float4 c = cv[i];
        float dx = P[j][i].x-c.x, dy = P[j][i].y-c.y, dz = P[j][i].z-c.z, dw = P[j][i].w-c.w;
        d += dx*dx; d += dy*dy; d += dz*dz; d += dw*dw;
      }
      dd[j] = d;
    }
    ull p0 = packPDI(phase, dd[0], n0);
    ull p1 = packPDI(phase, dd[1], n0 + 512);
    myp = p0 > p1 ? p0 : p1;
  }
  for (int it = 0; ; it++){
    // cross-block argmax of myp (phase-tagged)
    ull bp = waveMaxU64(myp);
    if (lane == 0) wv[w] = bp;
    __syncthreads();
    const int par = phase & 1;
    if (tid == 0){
      ull bb = wv[0];
#pragma unroll
      for (int q = 1; q < 8; q++) if (wv[q] > bb) bb = wv[q];
      atomicMax(&best[g*2 + par], bb);
      __threadfence();
      atomicAdd(cnt, 1);
      while (__hip_atomic_load(cnt, __ATOMIC_RELAXED, __HIP_MEMORY_SCOPE_AGENT) < 8*phase)
        __builtin_amdgcn_s_sleep(2);
      ull gb = __hip_atomic_load(&best[g*2 + par], __ATOMIC_ACQUIRE, __HIP_MEMORY_SCOPE_AGENT);
      sCur = unpackI(gb);
    }
    __syncthreads();
    int cur = sCur;
    if (it == 16) break;
    if (tid == 0) selS[it] = cur;
    if (tid < 16) ((float4*)cent)[tid] = ((const float4*)(pts + (size_t)cur*64))[tid];
    __syncthreads();
    phase++;
    float dd[2];
#pragma unroll
    for (int j = 0; j < 2; j++){
      float d = 0.f;
#pragma unroll
      for (int i = 0; i < 16; i++){
        float4 c = cv[i];
        float dx = P[j][i].x-c.x, dy = P[j][i].y-c.y, dz = P[j][i].z-c.z, dw = P[j][i].w-c.w;
        d += dx*dx; d += dy*dy; d += dz*dz; d += dw*dw;
      }
      md[j] = fminf(md[j], d);
      dd[j] = md[j];
    }
    ull p0 = packPDI(phase, dd[0], n0);
    ull p1 = packPDI(phase, dd[1], n0 + 512);
    myp = p0 > p1 ? p0 : p1;
    if (it == 15){ // last reduction round not needed beyond sel; but keep loop shape
    }
  }

  if (blk == 0){
    if (tid == 0){
      for (int i = 1; i < 16; i++){
        int key = selS[i]; int j = i - 1;
        while (j >= 0 && selS[j] > key){ selS[j+1] = selS[j]; j--; }
        selS[j+1] = key;
      }
    }
    __syncthreads();
    for (int idx = tid; idx < 1024; idx += 512)
      ws[OFF_SEL + g*1024 + idx] = pts[(size_t)selS[idx >> 6]*64 + (idx & 63)];
    __threadfence();
  }
  __syncthreads();
  if (tid == 0) atomicAdd(gcnt, 1);
  if (g != 0 || blk != 0) return;

  if (tid == 0){
    while (__hip_atomic_load(gcnt, __ATOMIC_RELAXED, __HIP_MEMORY_SCOPE_AGENT) < 24)
      __builtin_amdgcn_s_sleep(2);
    __threadfence();
  }
  __syncthreads();

  // ---- kG tail
  if (tid < 64){
    const float gw1 = ld(gWsa1, tid, bf);
    float wpec[64];
#pragma unroll
    for (int cn = 0; cn < 64; cn++) wpec[cn] = ld(gWpe, cn*64 + tid, bf);
    float lxs = ws[OFF_LXSUM + tid];
    float G = 0.f;
#pragma unroll
    for (int cn = 0; cn < 64; cn++) G += __shfl(lxs, cn, 64) * wpec[cn];
    GS[tid] = G;
    const float* selp = ws + OFF_SEL;
    for (int m = 0; m < 16; m++){
      float plx = selp[m*64 + tid];
      float g2 = 0.f;
#pragma unroll
      for (int cn = 0; cn < 64; cn++) g2 += __shfl(plx, cn, 64) * wpec[cn];
      gfS[m*64 + tid] = g2;
      float pkv = selp[1024 + m*64 + tid];
      float part = waveSum((pkv + g2) * gw1);
      if (tid == 0) betaS[m] = part;
    }
  }
  __syncthreads();
  if (tid < 64){
    float mx = -1e30f;
    for (int m = 0; m < 16; m++) mx = fmaxf(mx, -betaS[m]);
    float ssum = 0.f;
    for (int m = 0; m < 16; m++) ssum += expf(-betaS[m] - mx);
    float A = 0.f;
    for (int m = 0; m < 16; m++){
      float sg = expf(-betaS[m] - mx) / ssum;
      float pv = ws[OFF_SEL + 2048 + m*64 + tid];
      float Sg = 8192.0f * (pv - gfS[m*64 + tid]) + GS[tid];
      A += sg * Sg;
    }
    float cg = 0.f;
#pragma unroll
    for (int cn = 0; cn < 64; cn++) cg += __shfl(A, cn, 64) * ld(gWsa2, cn*64 + tid, bf);
    ws[OFF_CG + tid] = cg;
  }
}

// ---- kImg: 512 blocks, 16 rows each; LN + GELU + scatter-add
__global__ void __launch_bounds__(256, 3) kImg(const void* __restrict__ ev,
    const void* __restrict__ lnw, const void* __restrict__ lnb,
    float* __restrict__ ws, int b){
  const bool bf = isbf(ev);
  const int lane = threadIdx.x & 63, w = threadIdx.x >> 6;
  const float cg = ws[OFF_CG + lane];
  const float lw = ld(lnw, lane, bf), lb = ld(lnb, lane, bf);
  float* space = ws + OFF_SPACE;
#pragma unroll
  for (int i = 0; i < 4; i++){
    const int n = blockIdx.x*16 + w + 4*i;
    float x = ws[OFF_B + n*64 + lane] + cg;
    float mu = waveSum(x) * (1.0f/64.0f);
    float dv = x - mu;
    float var = waveSum(dv*dv) * (1.0f/64.0f);
    float xn = dv / sqrtf(var + 1e-5f);
    float y = xn * lw + lb;
    float h = 0.5f * y * (1.0f + erff(y * 0.70710678118654752f));
    const int e4 = (b*NB + n)*4;
    float exf = ld(ev, e4+0, bf), eyf = ld(ev, e4+1, bf), epf = ld(ev, e4+3, bf);
    int xi = (int)floorf(exf), yi = (int)floorf(eyf);
    int flat = yi*IMG_W + xi;
    flat = max(0, min(HWPIX-1, flat));
    atomicAdd(space + flat*64 + lane, epf * h);
  }
}

// ---- kStat: one float4 pass -> cnt, sum, sumsq
__global__ void __launch_bounds__(256) kStat(float* __restrict__ ws){
  const float4* sp = (const float4*)(ws + OFF_SPACE);
  float cnt = 0.f, sum = 0.f, ssq = 0.f;
  for (unsigned i = blockIdx.x*256u + threadIdx.x; i < SPB/4; i += gridDim.x*256u){
    float4 v = sp[i];
    if (v.x != 0.f){ cnt += 1.f; sum += v.x; ssq += v.x*v.x; }
    if (v.y != 0.f){ cnt += 1.f; sum += v.y; ssq += v.y*v.y; }
    if (v.z != 0.f){ cnt += 1.f; sum += v.z; ssq += v.z*v.z; }
    if (v.w != 0.f){ cnt += 1.f; sum += v.w; ssq += v.w*v.w; }
  }
  cnt = waveSum(cnt); sum = waveSum(sum); ssq = waveSum(ssq);
  __shared__ float rc[4], rs[4], rq[4];
  const int lane = threadIdx.x & 63, w = threadIdx.x >> 6;
  if (lane == 0){ rc[w] = cnt; rs[w] = sum; rq[w] = ssq; }
  __syncthreads();
  if (threadIdx.x == 0){
    atomicAdd(&ws[OFF_STATS + 0], rc[0]+rc[1]+rc[2]+rc[3]);
    atomicAdd(&ws[OFF_STATS + 1], rs[0]+rs[1]+rs[2]+rs[3]);
    atomicAdd(&ws[OFF_STATS + 2], rq[0]+rq[1]+rq[2]+rq[3]);
  }
}

// ---- kOut: LDS-transpose 64hw x 64c; var from sum/sumsq identity
__global__ void __launch_bounds__(256) kOut(const void* __restrict__ ev,
    const float* __restrict__ ws, void* __restrict__ out, int b){
  const bool bf = isbf(ev);
  __shared__ float tile[64*64];
  const int tid = threadIdx.x;
  const int hw0 = blockIdx.x*64;
#pragma unroll
  for (int i = 0; i < 16; i++){
    int idx = tid + 256*i;
    tile[idx] = ws[OFF_SPACE + (size_t)hw0*64 + idx];
  }
  const float cnt = ws[OFF_STATS + 0];
  const float sum = ws[OFF_STATS + 1];
  const float ssq = ws[OFF_STATS + 2];
  const float mean = sum / fmaxf(cnt, 1.f);
  const float m2   = fmaxf(ssq - sum*mean, 0.f);   // == sum((x-mean)^2) over nonzero
  const float var  = m2 / fmaxf(cnt - 1.f, 1.f);
  const float stdv = sqrtf(var);
  __syncthreads();
  const int c = tid >> 2, sub = tid & 3;
#pragma unroll
  for (int j = 0; j < 16; j++){
    int hwl = sub*16 + j;
    float x = tile[hwl*64 + c];
    float centered = (x != 0.f) ? (x - mean) : x;
    float normed = (stdv > 0.f) ? (centered / stdv) : centered;
    float o = (cnt > 0.f) ? normed : x;
    stout(out, (long)(b*64 + c)*HWPIX + hw0 + hwl, o, bf);
  }
}

extern "C" void kernel_launch(void* const* d_in, const int* in_sizes, int n_in,
                              void* d_out, int out_size, void* d_ws, size_t ws_size,
                              hipStream_t stream){
  (void)in_sizes; (void)n_in; (void)out_size; (void)ws_size;
  const void* ev     = d_in[0];
  const void* Wm     = d_in[1];
  const void* Wpe    = d_in[2];
  const void* lnw    = d_in[3];
  const void* lnb    = d_in[4];
  const void* lxWq   = d_in[5];
  const void* lxWk   = d_in[6];
  const void* lxWv   = d_in[7];
  const void* lxWsa1 = d_in[8];
  const void* lxWsa2 = d_in[9];
  // d_in[10] = gx_Wq : unused (cancels in n-independent softmax)
  const void* gxWk   = d_in[11];
  const void* gxWv   = d_in[12];
  const void* gxWpe  = d_in[13];
  const void* gxWsa1 = d_in[14];
  const void* gxWsa2 = d_in[15];
  float* ws = (float*)d_ws;

  kW<<<1, 64, 0, stream>>>(ev, lxWq, lxWk, Wpe, lxWsa1, ws);
  for (int b = 0; b < NBATCH; b++){
    kZeroSmall<<<1, 256, 0, stream>>>(ws);
    kA<<<512, 256, 0, stream>>>(ev, Wm, Wpe, lxWv, ws, b);
    kB<<<16, 64, 0, stream>>>(ws);
    kC<<<512, 256, 0, stream>>>(ev, lxWsa2, gxWk, gxWv, ws);
    kFPS<<<dim3(8, 3), 512, 0, stream>>>(ev, gxWk, gxWv, gxWpe, gxWsa1, gxWsa2, ws);
    kZeroSpace<<<SPB/4/256, 256, 0, stream>>>(ws);
    kImg<<<512, 256, 0, stream>>>(ev, lnw, lnb, ws, b);
    kStat<<<256, 256, 0, stream>>>(ws);
    kOut<<<675, 256, 0, stream>>>(ev, ws, d_out, b);
  }
}

// Round 7
// 613.403 us; speedup vs baseline: 6.5914x; 1.2993x over previous
//
#include <hip/hip_runtime.h>

// EventTransformer on MI355X. B=2, N=8192, C=CN=64, M=16, H=180, W=240.
// fp32 internal in d_ws (~13.3 MB, batches sequential). I/O dtype (fp32/bf16)
// runtime-detected from events word 3 (p0 == +-1.0f exactly iff fp32).
//
// R7: (a) VSUM via ESUM algebra (kA atomic-free & light; kE added);
// (b) LXSUM via per-block partials (no RMW), reduced in kFPS head;
// (c) kA/kC/kImg at 1024 blocks, split accumulator chains;
// (d) kFPS release-word barrier + XCD-affinity groups (g = blk%8).

typedef unsigned short u16;
typedef unsigned long long ull;

#define NB 8192
#define NBATCH 2
#define IMG_H 180
#define IMG_W 240
#define HWPIX (IMG_H*IMG_W)          // 43200
#define SPB (HWPIX*64)               // 2,764,800 floats
#define NC (NB*64)                   // 524,288

#define OFF_SPACE 0
#define OFF_A     0                  // lx_in -> kg  (dead before space zero)
#define OFF_C     NC                 // vg           (dead before space zero)
#define OFF_LXP   (2*NC)             // 1024x64 lx_out block partials (inside SPACE gap)
#define OFF_B     SPB                // lx_out       (lives through kImg)
#define SMB       (SPB + NC)         // 3,289,088
#define OFF_AC    (SMB)
#define OFF_T     (SMB + 8192)
#define OFF_ZERO  (SMB + 16384)
#define OFF_STATS (OFF_ZERO)         // 3 used
#define OFF_ESUM  (OFF_ZERO + 4)     // 4
#define OFF_SYNC  (OFF_ZERO + 16)    // per-group 16 floats: cnt,rel,pad,pad,best[2]
#define OFF_GCNT  (OFF_ZERO + 64)    // own cacheline
#define ZERO_CNT  80
#define OFF_SEL   (SMB + 16544)      // 3*16*64
#define OFF_CG    (SMB + 19616)      // 64
#define OFF_W1    (SMB + 19680)      // 192
#define OFF_EDGEV (SMB + 19872)      // 16*64
#define OFF_EDGEF (SMB + 20896)      // 16*64
#define OFF_S     (SMB + 21920)      // 16*64
#define WS_FLOATS (SMB + 22944)      // ~13.25 MB

__device__ __forceinline__ float bf2f(u16 u){
  union { unsigned int i; float f; } w; w.i = ((unsigned int)u) << 16; return w.f;
}
__device__ __forceinline__ u16 f2bf(float f){
  union { unsigned int i; float f; } w; w.f = f;
  unsigned int x = w.i;
  x += 0x7fffu + ((x >> 16) & 1u);   // RNE
  return (u16)(x >> 16);
}
__device__ __forceinline__ bool isbf(const void* ev){
  unsigned w3 = ((const unsigned*)ev)[3];
  return !(w3 == 0x3F800000u || w3 == 0xBF800000u);
}
__device__ __forceinline__ float ld(const void* p, int i, bool bf){
  return bf ? bf2f(((const u16*)p)[i]) : ((const float*)p)[i];
}
__device__ __forceinline__ void stout(void* o, long i, float v, bool bf){
  if (bf) ((u16*)o)[i] = f2bf(v); else ((float*)o)[i] = v;
}
__device__ __forceinline__ float waveSum(float v){
#pragma unroll
  for (int m = 1; m < 64; m <<= 1) v += __shfl_xor(v, m, 64);
  return v;
}
__device__ __forceinline__ ull waveMaxU64(ull v){
#pragma unroll
  for (int m = 1; m < 64; m <<= 1){
    ull o = (ull)__shfl_xor((long long)v, m, 64);
    if (o > v) v = o;
  }
  return v;
}
// pack: [52:45]=phase, [44:13]=dist bits (d>=0), [12:0]=8191-idx (tie->min idx)
__device__ __forceinline__ ull packPDI(int phase, float d, int n){
  return ((ull)phase << 45) | ((ull)__float_as_uint(d) << 13) | (ull)(8191 - n);
}
__device__ __forceinline__ int unpackI(ull p){ return 8191 - (int)(p & 0x1FFFull); }

__global__ void kZeroSmall(float* __restrict__ ws){
  if (threadIdx.x < ZERO_CNT) ws[OFF_ZERO + threadIdx.x] = 0.f;
}
__global__ void kZeroSpace(float* __restrict__ ws){
  float4 z = make_float4(0.f, 0.f, 0.f, 0.f);
  ((float4*)(ws + OFF_SPACE))[blockIdx.x*256 + threadIdx.x] = z;
}

// ---- kE: ESUM[i] = sum_n events[b,n,i]  (8 blocks)
__global__ void __launch_bounds__(256) kE(const void* __restrict__ ev,
                                          float* __restrict__ ws, int b){
  const bool bf = isbf(ev);
  const int lane = threadIdx.x & 63, w = threadIdx.x >> 6;
  float s0 = 0.f, s1 = 0.f, s2 = 0.f, s3 = 0.f;
#pragma unroll
  for (int j = 0; j < 4; j++){
    int r = blockIdx.x*256 + threadIdx.x + 2048*j;
    const int e4 = (b*NB + r)*4;
    s0 += ld(ev, e4+0, bf); s1 += ld(ev, e4+1, bf);
    s2 += ld(ev, e4+2, bf); s3 += ld(ev, e4+3, bf);
  }
  s0 = waveSum(s0); s1 = waveSum(s1); s2 = waveSum(s2); s3 = waveSum(s3);
  __shared__ float r4[4][4];
  if (lane == 0){ r4[w][0]=s0; r4[w][1]=s1; r4[w][2]=s2; r4[w][3]=s3; }
  __syncthreads();
  if (threadIdx.x < 4)
    atomicAdd(&ws[OFF_ESUM + threadIdx.x],
              r4[0][threadIdx.x]+r4[1][threadIdx.x]+r4[2][threadIdx.x]+r4[3][threadIdx.x]);
}

// ---- kW: wq1 = Wq@Wsa1, wk1 = Wk@Wsa1, wpe1 = Wpe@Wsa1 (once)
__global__ void kW(const void* __restrict__ ev, const void* __restrict__ Wq,
                   const void* __restrict__ Wk, const void* __restrict__ Wpe,
                   const void* __restrict__ w1, float* __restrict__ ws){
  const bool bf = isbf(ev);
  const int lane = threadIdx.x;  // 64
  float s1 = 0.f, s2 = 0.f;
  for (int c = 0; c < 64; c++){
    float wc = ld(w1, c, bf);
    s1 += ld(Wq, lane*64 + c, bf) * wc;
    s2 += ld(Wk, lane*64 + c, bf) * wc;
  }
  ws[OFF_W1 + lane] = s1;
  ws[OFF_W1 + 64 + lane] = s2;
  if (lane < 4){
    float s3 = 0.f;
    for (int c = 0; c < 64; c++) s3 += ld(Wpe, lane*64 + c, bf) * ld(w1, c, bf);
    ws[OFF_W1 + 128 + lane] = s3;
  }
}

// ---- kA: 1024 blocks, 8 rows each (2 rows/wave). No atomics; edge v/f only.
__global__ void __launch_bounds__(256, 4) kA(const void* __restrict__ ev,
    const void* __restrict__ Wm, const void* __restrict__ Wpe,
    const void* __restrict__ Wv, float* __restrict__ ws, int b){
  const bool bf = isbf(ev);
  const int lane = threadIdx.x & 63, w = threadIdx.x >> 6;
  const float wq1 = ws[OFF_W1 + lane];
  const float wk1 = ws[OFF_W1 + 64 + lane];
  const float wp10 = ws[OFF_W1+128], wp11 = ws[OFF_W1+129],
              wp12 = ws[OFF_W1+130], wp13 = ws[OFF_W1+131];
  float wmc[4];
#pragma unroll
  for (int j = 0; j < 4; j++) wmc[j] = ld(Wm, j*64+lane, bf);
  const bool edgeBlk = (blockIdx.x == 0 || blockIdx.x == 1023);
  float wpc[4], wvc[64];
  if (edgeBlk){
#pragma unroll
    for (int j = 0; j < 4; j++) wpc[j] = ld(Wpe, j*64+lane, bf);
#pragma unroll
    for (int cn = 0; cn < 64; cn++) wvc[cn] = ld(Wv, cn*64+lane, bf);
  }
#pragma unroll
  for (int i = 0; i < 2; i++){
    const int n = blockIdx.x*8 + w + 4*i;
    const int e4 = (b*NB + n)*4;
    float e0 = ld(ev, e4+0, bf), e1 = ld(ev, e4+1, bf),
          e2 = ld(ev, e4+2, bf), e3 = ld(ev, e4+3, bf);
    float lx = e0*wmc[0] + e1*wmc[1] + e2*wmc[2] + e3*wmc[3];
    float epe = e0*wp10 + e1*wp11 + e2*wp12 + e3*wp13;
    float acv = waveSum(lx * wq1) + epe;
    float tv  = waveSum(lx * wk1) + epe;
    ws[OFF_A + n*64 + lane] = lx;
    if (lane == 0){ ws[OFF_AC + n] = acv; ws[OFF_T + n] = tv; }
    if (edgeBlk && (n < 8 || n >= NB-8)){
      int e = (n < 8) ? n : (n - (NB-16));
      float v = 0.f;
#pragma unroll
      for (int cn = 0; cn < 64; cn++) v += __shfl(lx, cn, 64) * wvc[cn];
      float f = e0*wpc[0] + e1*wpc[1] + e2*wpc[2] + e3*wpc[3];
      ws[OFF_EDGEV + e*64 + lane] = v;
      ws[OFF_EDGEF + e*64 + lane] = f;
    }
  }
}

// ---- kB: VSUM from ESUM algebra; S[m,c] = VSUM[c] - excl_v(m) + excl_f(m)
__global__ void __launch_bounds__(64) kB(const void* __restrict__ ev,
    const void* __restrict__ Wm, const void* __restrict__ Wv,
    float* __restrict__ ws){
  const bool bf = isbf(ev);
  const int m = blockIdx.x, lane = threadIdx.x;
  // lxin_sum[c] = sum_i ESUM[i]*Wm[i][c];  VSUM[c] = sum_j lxin_sum[j]*Wv[j][c]
  float tm = 0.f;
#pragma unroll
  for (int i = 0; i < 4; i++) tm += ws[OFF_ESUM + i] * ld(Wm, i*64 + lane, bf);
  float vs0 = 0.f, vs1 = 0.f;
#pragma unroll
  for (int j = 0; j < 64; j += 2){
    vs0 += __shfl(tm, j, 64)   * ld(Wv, j*64 + lane, bf);
    vs1 += __shfl(tm, j+1, 64) * ld(Wv, (j+1)*64 + lane, bf);
  }
  float vsum = vs0 + vs1;
  const int d = m - 8;
  float sv = 0.f, sf = 0.f;
  if (d < 0){
    for (int e = 16 + d; e < 16; e++){ sv += ws[OFF_EDGEV+e*64+lane]; sf += ws[OFF_EDGEF+e*64+lane]; }
  } else {
    for (int e = 0; e < d; e++){ sv += ws[OFF_EDGEV+e*64+lane]; sf += ws[OFF_EDGEF+e*64+lane]; }
  }
  ws[OFF_S + m*64 + lane] = vsum - sv + sf;
}

// ---- kC: 1024 blocks, 8 rows each; softmax; lx_out; kg/vg; LXP partial store
__global__ void __launch_bounds__(256, 4) kC(const void* __restrict__ ev,
    const void* __restrict__ Wsa2, const void* __restrict__ gWk,
    const void* __restrict__ gWv, float* __restrict__ ws){
  const bool bf = isbf(ev);
  __shared__ float S_lds[1024];
  __shared__ float lred[4][64];
  const int tid = threadIdx.x, lane = tid & 63, w = tid >> 6;
  for (int i = tid; i < 1024; i += 256) S_lds[i] = ws[OFF_S + i];
  __syncthreads();
  float wcol[64];
#pragma unroll
  for (int cn = 0; cn < 64; cn++) wcol[cn] = ld(Wsa2, cn*64 + lane, bf);
  float lxoR[2];
  float lxsum = 0.f;
#pragma unroll
  for (int i = 0; i < 2; i++){
    const int n = blockIdx.x*8 + w + 4*i;
    float lx  = ws[OFF_A + n*64 + lane];
    float acn = ws[OFF_AC + n];
    const int m = lane & 15;
    const int j = n + m - 8;
    float tv = (j >= 0 && j < NB) ? ws[OFF_T + j] : 0.f;
    float logit = acn - tv;
    float mx = logit;
#pragma unroll
    for (int k = 1; k < 16; k <<= 1) mx = fmaxf(mx, __shfl_xor(mx, k, 64));
    float ex = expf(logit - mx);
    float sm = ex;
#pragma unroll
    for (int k = 1; k < 16; k <<= 1) sm += __shfl_xor(sm, k, 64);
    float sig = ex / sm;
    float pat = 0.f;
#pragma unroll
    for (int mm = 0; mm < 16; mm++) pat += __shfl(sig, mm, 64) * S_lds[mm*64 + lane];
    float sa0 = 0.f, sa1 = 0.f;
#pragma unroll
    for (int cn = 0; cn < 64; cn += 2){
      sa0 += __shfl(pat, cn, 64)   * wcol[cn];
      sa1 += __shfl(pat, cn+1, 64) * wcol[cn+1];
    }
    float lxo = lx + sa0 + sa1;
    lxoR[i] = lxo;
    ws[OFF_B + n*64 + lane] = lxo;
    lxsum += lxo;
  }
  lred[w][lane] = lxsum;
#pragma unroll
  for (int cn = 0; cn < 64; cn++) wcol[cn] = ld(gWk, cn*64 + lane, bf);
#pragma unroll
  for (int i = 0; i < 2; i++){
    const int n = blockIdx.x*8 + w + 4*i;
    float k0 = 0.f, k1 = 0.f;
#pragma unroll
    for (int cn = 0; cn < 64; cn += 2){
      k0 += __shfl(lxoR[i], cn, 64)   * wcol[cn];
      k1 += __shfl(lxoR[i], cn+1, 64) * wcol[cn+1];
    }
    ws[OFF_A + n*64 + lane] = k0 + k1;
  }
#pragma unroll
  for (int cn = 0; cn < 64; cn++) wcol[cn] = ld(gWv, cn*64 + lane, bf);
#pragma unroll
  for (int i = 0; i < 2; i++){
    const int n = blockIdx.x*8 + w + 4*i;
    float v0 = 0.f, v1 = 0.f;
#pragma unroll
    for (int cn = 0; cn < 64; cn += 2){
      v0 += __shfl(lxoR[i], cn, 64)   * wcol[cn];
      v1 += __shfl(lxoR[i], cn+1, 64) * wcol[cn+1];
    }
    ws[OFF_C + n*64 + lane] = v0 + v1;
  }
  __syncthreads();
  if (tid < 64)
    ws[OFF_LXP + blockIdx.x*64 + tid] = lred[0][tid]+lred[1][tid]+lred[2][tid]+lred[3][tid];
}

// ---- kFPS: 64 linear blocks; active: blk%8 in {0,1,2} -> g, idx=blk/8 (XCD affinity).
// Head: LXSUM from partials; bary analytically. Barrier: release word (phase|cur).
// Tail (blk 0): kG.
__global__ void __launch_bounds__(512) kFPS(const void* __restrict__ ev,
    const void* __restrict__ gWk, const void* __restrict__ gWv,
    const void* __restrict__ gWpe, const void* __restrict__ gWsa1,
    const void* __restrict__ gWsa2, float* __restrict__ ws){
  const int g = blockIdx.x & 7;
  if (g >= 3) return;
  const int idx = blockIdx.x >> 3;     // 0..7
  const int tid = threadIdx.x, lane = tid & 63, w = tid >> 6;
  const float* pts = ws + (g == 0 ? OFF_B : g == 1 ? OFF_A : OFF_C);
  int* syncb = (int*)(ws + OFF_SYNC + g*16);
  int* cnt = syncb + 0;
  int* rel = syncb + 1;
  ull* best = (ull*)(syncb + 4);       // [parity]
  int* gcnt = (int*)(ws + OFF_GCNT);

  __shared__ float cent[64];
  __shared__ float red[8][64];
  __shared__ float lxsS[64];
  __shared__ ull   wv[8];
  __shared__ int   selS[16];
  __shared__ int   sCur;
  __shared__ float gfS[1024];
  __shared__ float betaS[16];
  __shared__ float GS[64];

  const int n0 = idx*1024 + tid;       // +0 and +512
  float4 P[2][16];
#pragma unroll
  for (int j = 0; j < 2; j++)
#pragma unroll
    for (int i = 0; i < 16; i++)
      P[j][i] = ((const float4*)(pts + (size_t)(n0 + j*512)*64))[i];

  // head: LXSUM = sum of 1024 block partials
  {
    const int c = tid & 63, grp = tid >> 6;
    float s = 0.f;
    for (int b2 = grp; b2 < 1024; b2 += 8) s += ws[OFF_LXP + b2*64 + c];
    red[grp][c] = s;
  }
  __syncthreads();
  const bool bf = isbf(ev);
  if (tid < 64){
    float lxs = 0.f;
#pragma unroll
    for (int q = 0; q < 8; q++) lxs += red[q][tid];
    lxsS[tid] = lxs;
    float c;
    if (g == 0) c = lxs * (1.0f/NB);
    else {
      const void* W = (g == 1) ? gWk : gWv;
      float s = 0.f;
#pragma unroll
      for (int j = 0; j < 64; j++) s += __shfl(lxs, j, 64) * ld(W, j*64 + tid, bf);
      c = s * (1.0f/NB);
    }
    cent[tid] = c;
  }
  __syncthreads();

  const float4* cv = (const float4*)cent;
  float md[2] = {1e10f, 1e10f};
  int cur;
  // farthest0
  {
    float dd[2];
#pragma unroll
    for (int j = 0; j < 2; j++){
      float d = 0.f;
#pragma unroll
      for (int i = 0; i < 16; i++){
        float4 c = cv[i];
        float dx = P[j][i].x-c.x, dy = P[j][i].y-c.y, dz = P[j][i].z-c.z, dw = P[j][i].w-c.w;
        d += dx*dx; d += dy*dy; d += dz*dz; d += dw*dw;
      }
      dd[j] = d;
    }
    ull p0 = packPDI(1, dd[0], n0);
    ull p1 = packPDI(1, dd[1], n0 + 512);
    ull bp = waveMaxU64(p0 > p1 ? p0 : p1);
    if (lane == 0) wv[w] = bp;
    __syncthreads();
    if (tid == 0){
      ull bb = wv[0];
#pragma unroll
      for (int q = 1; q < 8; q++) if (wv[q] > bb) bb = wv[q];
      atomicMax(&best[1], bb);
      __threadfence();
      int old = atomicAdd(cnt, 1);
      if (old == 7){
        __threadfence();
        ull gb = __hip_atomic_load(&best[1], __ATOMIC_ACQUIRE, __HIP_MEMORY_SCOPE_AGENT);
        int cc = unpackI(gb);
        __hip_atomic_store(rel, (1 << 16) | cc, __ATOMIC_RELEASE, __HIP_MEMORY_SCOPE_AGENT);
        sCur = cc;
      } else {
        int r;
        do { r = __hip_atomic_load(rel, __ATOMIC_RELAXED, __HIP_MEMORY_SCOPE_AGENT);
             if ((r >> 16) == 1) break; __builtin_amdgcn_s_sleep(1); } while (1);
        sCur = r & 0xFFFF;
      }
    }
    __syncthreads();
    cur = sCur;
  }

  for (int it = 0; ; it++){
    if (tid == 0) selS[it] = cur;
    if (it == 15) break;
    if (tid < 16) ((float4*)cent)[tid] = ((const float4*)(pts + (size_t)cur*64))[tid];
    __syncthreads();
    const int phase = it + 2;
    float dd[2];
#pragma unroll
    for (int j = 0; j < 2; j++){
      float d = 0.f;
#pragma unroll
      for (int i = 0; i < 16; i++){
        float4 c = cv[i];
        float dx = P[j][i].x-c.x, dy = P[j][i].y-c.y, dz = P[j][i].z-c.z, dw = P[j][i].w-c.w;
        d += dx*dx; d += dy*dy; d += dz*dz; d += dw*dw;
      }
      md[j] = fminf(md[j], d);
      dd[j] = md[j];
    }
    ull p0 = packPDI(phase, dd[0], n0);
    ull p1 = packPDI(phase, dd[1], n0 + 512);
    ull bp = waveMaxU64(p0 > p1 ? p0 : p1);
    if (lane == 0) wv[w] = bp;
    __syncthreads();
    const int par = phase & 1;
    if (tid == 0){
      ull bb = wv[0];
#pragma unroll
      for (int q = 1; q < 8; q++) if (wv[q] > bb) bb = wv[q];
      atomicMax(&best[par], bb);
      __threadfence();
      int old = atomicAdd(cnt, 1);
      if (old == 8*phase - 1){
        __threadfence();
        ull gb = __hip_atomic_load(&best[par], __ATOMIC_ACQUIRE, __HIP_MEMORY_SCOPE_AGENT);
        int cc = unpackI(gb);
        __hip_atomic_store(rel, (phase << 16) | cc, __ATOMIC_RELEASE, __HIP_MEMORY_SCOPE_AGENT);
        sCur = cc;
      } else {
        int r;
        do { r = __hip_atomic_load(rel, __ATOMIC_RELAXED, __HIP_MEMORY_SCOPE_AGENT);
             if ((r >> 16) == phase) break; __builtin_amdgcn_s_sleep(1); } while (1);
        sCur = r & 0xFFFF;
      }
    }
    __syncthreads();
    cur = sCur;
  }
  __syncthreads();

  if (idx == 0){
    if (tid == 0){
      for (int i = 1; i < 16; i++){
        int key = selS[i]; int j = i - 1;
        while (j >= 0 && selS[j] > key){ selS[j+1] = selS[j]; j--; }
        selS[j+1] = key;
      }
    }
    __syncthreads();
    for (int idx2 = tid; idx2 < 1024; idx2 += 512)
      ws[OFF_SEL + g*1024 + idx2] = pts[(size_t)selS[idx2 >> 6]*64 + (idx2 & 63)];
    __threadfence();
  }
  __syncthreads();
  if (tid == 0) atomicAdd(gcnt, 1);
  if (g != 0 || idx != 0) return;

  if (tid == 0){
    while (__hip_atomic_load(gcnt, __ATOMIC_RELAXED, __HIP_MEMORY_SCOPE_AGENT) < 24)
      __builtin_amdgcn_s_sleep(1);
    __threadfence();
  }
  __syncthreads();

  // ---- kG tail
  if (tid < 64){
    const float gw1 = ld(gWsa1, tid, bf);
    float wpec[64];
#pragma unroll
    for (int cn = 0; cn < 64; cn++) wpec[cn] = ld(gWpe, cn*64 + tid, bf);
    float lxs = lxsS[tid];
    float G = 0.f;
#pragma unroll
    for (int cn = 0; cn < 64; cn++) G += __shfl(lxs, cn, 64) * wpec[cn];
    GS[tid] = G;
    const float* selp = ws + OFF_SEL;
    for (int m = 0; m < 16; m++){
      float plx = selp[m*64 + tid];
      float g2 = 0.f;
#pragma unroll
      for (int cn = 0; cn < 64; cn++) g2 += __shfl(plx, cn, 64) * wpec[cn];
      gfS[m*64 + tid] = g2;
      float pkv = selp[1024 + m*64 + tid];
      float part = waveSum((pkv + g2) * gw1);
      if (tid == 0) betaS[m] = part;
    }
  }
  __syncthreads();
  if (tid < 64){
    float mx = -1e30f;
    for (int m = 0; m < 16; m++) mx = fmaxf(mx, -betaS[m]);
    float ssum = 0.f;
    for (int m = 0; m < 16; m++) ssum += expf(-betaS[m] - mx);
    float A = 0.f;
    for (int m = 0; m < 16; m++){
      float sg = expf(-betaS[m] - mx) / ssum;
      float pv = ws[OFF_SEL + 2048 + m*64 + tid];
      float Sg = 8192.0f * (pv - gfS[m*64 + tid]) + GS[tid];
      A += sg * Sg;
    }
    float cg = 0.f;
#pragma unroll
    for (int cn = 0; cn < 64; cn++) cg += __shfl(A, cn, 64) * ld(gWsa2, cn*64 + tid, bf);
    ws[OFF_CG + tid] = cg;
  }
}

// ---- kImg: 1024 blocks, 8 rows each; LN + GELU + scatter-add
__global__ void __launch_bounds__(256, 4) kImg(const void* __restrict__ ev,
    const void* __restrict__ lnw, const void* __restrict__ lnb,
    float* __restrict__ ws, int b){
  const bool bf = isbf(ev);
  const int lane = threadIdx.x & 63, w = threadIdx.x >> 6;
  const float cg = ws[OFF_CG + lane];
  const float lw = ld(lnw, lane, bf), lb = ld(lnb, lane, bf);
  float* space = ws + OFF_SPACE;
#pragma unroll
  for (int i = 0; i < 2; i++){
    const int n = blockIdx.x*8 + w + 4*i;
    float x = ws[OFF_B + n*64 + lane] + cg;
    float mu = waveSum(x) * (1.0f/64.0f);
    float dv = x - mu;
    float var = waveSum(dv*dv) * (1.0f/64.0f);
    float xn = dv / sqrtf(var + 1e-5f);
    float y = xn * lw + lb;
    float h = 0.5f * y * (1.0f + erff(y * 0.70710678118654752f));
    const int e4 = (b*NB + n)*4;
    float exf = ld(ev, e4+0, bf), eyf = ld(ev, e4+1, bf), epf = ld(ev, e4+3, bf);
    int xi = (int)floorf(exf), yi = (int)floorf(eyf);
    int flat = yi*IMG_W + xi;
    flat = max(0, min(HWPIX-1, flat));
    atomicAdd(space + flat*64 + lane, epf * h);
  }
}

// ---- kStat: one float4 pass -> cnt, sum, sumsq
__global__ void __launch_bounds__(256) kStat(float* __restrict__ ws){
  const float4* sp = (const float4*)(ws + OFF_SPACE);
  float cnt = 0.f, sum = 0.f, ssq = 0.f;
  for (unsigned i = blockIdx.x*256u + threadIdx.x; i < SPB/4; i += gridDim.x*256u){
    float4 v = sp[i];
    if (v.x != 0.f){ cnt += 1.f; sum += v.x; ssq += v.x*v.x; }
    if (v.y != 0.f){ cnt += 1.f; sum += v.y; ssq += v.y*v.y; }
    if (v.z != 0.f){ cnt += 1.f; sum += v.z; ssq += v.z*v.z; }
    if (v.w != 0.f){ cnt += 1.f; sum += v.w; ssq += v.w*v.w; }
  }
  cnt = waveSum(cnt); sum = waveSum(sum); ssq = waveSum(ssq);
  __shared__ float rc[4], rs[4], rq[4];
  const int lane = threadIdx.x & 63, w = threadIdx.x >> 6;
  if (lane == 0){ rc[w] = cnt; rs[w] = sum; rq[w] = ssq; }
  __syncthreads();
  if (threadIdx.x == 0){
    atomicAdd(&ws[OFF_STATS + 0], rc[0]+rc[1]+rc[2]+rc[3]);
    atomicAdd(&ws[OFF_STATS + 1], rs[0]+rs[1]+rs[2]+rs[3]);
    atomicAdd(&ws[OFF_STATS + 2], rq[0]+rq[1]+rq[2]+rq[3]);
  }
}

// ---- kOut: LDS-transpose 64hw x 64c; var from sum/sumsq identity
__global__ void __launch_bounds__(256) kOut(const void* __restrict__ ev,
    const float* __restrict__ ws, void* __restrict__ out, int b){
  const bool bf = isbf(ev);
  __shared__ float tile[64*64];
  const int tid = threadIdx.x;
  const int hw0 = blockIdx.x*64;
#pragma unroll
  for (int i = 0; i < 16; i++){
    int idx = tid + 256*i;
    tile[idx] = ws[OFF_SPACE + (size_t)hw0*64 + idx];
  }
  const float cnt = ws[OFF_STATS + 0];
  const float sum = ws[OFF_STATS + 1];
  const float ssq = ws[OFF_STATS + 2];
  const float mean = sum / fmaxf(cnt, 1.f);
  const float m2   = fmaxf(ssq - sum*mean, 0.f);
  const float var  = m2 / fmaxf(cnt - 1.f, 1.f);
  const float stdv = sqrtf(var);
  __syncthreads();
  const int c = tid >> 2, sub = tid & 3;
#pragma unroll
  for (int j = 0; j < 16; j++){
    int hwl = sub*16 + j;
    float x = tile[hwl*64 + c];
    float centered = (x != 0.f) ? (x - mean) : x;
    float normed = (stdv > 0.f) ? (centered / stdv) : centered;
    float o = (cnt > 0.f) ? normed : x;
    stout(out, (long)(b*64 + c)*HWPIX + hw0 + hwl, o, bf);
  }
}

extern "C" void kernel_launch(void* const* d_in, const int* in_sizes, int n_in,
                              void* d_out, int out_size, void* d_ws, size_t ws_size,
                              hipStream_t stream){
  (void)in_sizes; (void)n_in; (void)out_size; (void)ws_size;
  const void* ev     = d_in[0];
  const void* Wm     = d_in[1];
  const void* Wpe    = d_in[2];
  const void* lnw    = d_in[3];
  const void* lnb    = d_in[4];
  const void* lxWq   = d_in[5];
  const void* lxWk   = d_in[6];
  const void* lxWv   = d_in[7];
  const void* lxWsa1 = d_in[8];
  const void* lxWsa2 = d_in[9];
  // d_in[10] = gx_Wq : unused (cancels in n-independent softmax)
  const void* gxWk   = d_in[11];
  const void* gxWv   = d_in[12];
  const void* gxWpe  = d_in[13];
  const void* gxWsa1 = d_in[14];
  const void* gxWsa2 = d_in[15];
  float* ws = (float*)d_ws;

  kW<<<1, 64, 0, stream>>>(ev, lxWq, lxWk, Wpe, lxWsa1, ws);
  for (int b = 0; b < NBATCH; b++){
    kZeroSmall<<<1, 256, 0, stream>>>(ws);
    kE<<<8, 256, 0, stream>>>(ev, ws, b);
    kA<<<1024, 256, 0, stream>>>(ev, Wm, Wpe, lxWv, ws, b);
    kB<<<16, 64, 0, stream>>>(ev, Wm, lxWv, ws);
    kC<<<1024, 256, 0, stream>>>(ev, lxWsa2, gxWk, gxWv, ws);
    kFPS<<<64, 512, 0, stream>>>(ev, gxWk, gxWv, gxWpe, gxWsa1, gxWsa2, ws);
    kZeroSpace<<<SPB/4/256, 256, 0, stream>>>(ws);
    kImg<<<1024, 256, 0, stream>>>(ev, lnw, lnb, ws, b);
    kStat<<<256, 256, 0, stream>>>(ws);
    kOut<<<675, 256, 0, stream>>>(ev, ws, d_out, b);
  }
}

// Round 8
// 446.452 us; speedup vs baseline: 9.0562x; 1.3740x over previous
//
#include <hip/hip_runtime.h>

// EventTransformer on MI355X. B=2, N=8192, C=CN=64, M=16, H=180, W=240.
// fp32 internal in d_ws. I/O dtype (fp32/bf16) runtime-detected.
//
// R8: (a) leaderless kFPS barrier — per-block slots in ONE cacheline,
// lane-parallel polling, no leader serialization, no fences in loop;
// (b) both batches in flight (grid.z=2) when ws_size allows (~26.5 MB layout,
// runtime fallback to 13.3 MB sequential layout); launches 21 -> 10.

typedef unsigned short u16;
typedef unsigned long long ull;

#define NB 8192
#define IMG_H 180
#define IMG_W 240
#define HWPIX (IMG_H*IMG_W)          // 43200
#define SPB (HWPIX*64)               // 2,764,800 floats
#define NC (NB*64)                   // 524,288

// tail-relative offsets (floats), per-batch strides noted
#define TT_AC    0        // +bb*8192
#define TT_T     16384    // +bb*8192
#define TT_W1    32768
#define TT_EDGEV 32960    // +bb*1024
#define TT_EDGEF 35008    // +bb*1024
#define TT_S     37056    // +bb*1024
#define TT_SEL   39104    // +bb*3072
#define TT_CG    45248    // +bb*64
#define TT_ESUM  45376    // +bb*16
#define TT_STATS 45408    // +bb*16
#define TT_SYNC  45440    // +(bb*3+g)*32 ; [par][blk] 2x8 ull
#define TT_GCNT  45632    // +bb*16
#define TT_ZOFF  45376
#define TT_ZCNT  288
#define TT_TOT   45664

__device__ __forceinline__ float bf2f(u16 u){
  union { unsigned int i; float f; } w; w.i = ((unsigned int)u) << 16; return w.f;
}
__device__ __forceinline__ u16 f2bf(float f){
  union { unsigned int i; float f; } w; w.f = f;
  unsigned int x = w.i;
  x += 0x7fffu + ((x >> 16) & 1u);   // RNE
  return (u16)(x >> 16);
}
__device__ __forceinline__ bool isbf(const void* ev){
  unsigned w3 = ((const unsigned*)ev)[3];
  return !(w3 == 0x3F800000u || w3 == 0xBF800000u);
}
__device__ __forceinline__ float ld(const void* p, int i, bool bf){
  return bf ? bf2f(((const u16*)p)[i]) : ((const float*)p)[i];
}
__device__ __forceinline__ void stout(void* o, long i, float v, bool bf){
  if (bf) ((u16*)o)[i] = f2bf(v); else ((float*)o)[i] = v;
}
__device__ __forceinline__ float waveSum(float v){
#pragma unroll
  for (int m = 1; m < 64; m <<= 1) v += __shfl_xor(v, m, 64);
  return v;
}
__device__ __forceinline__ ull waveMaxU64(ull v){
#pragma unroll
  for (int m = 1; m < 64; m <<= 1){
    ull o = (ull)__shfl_xor((long long)v, m, 64);
    if (o > v) v = o;
  }
  return v;
}
// pack: [52:45]=phase, [44:13]=dist bits (d>=0), [12:0]=8191-idx (tie->min idx)
__device__ __forceinline__ ull packPDI(int phase, float d, int n){
  return ((ull)phase << 45) | ((ull)__float_as_uint(d) << 13) | (ull)(8191 - n);
}
__device__ __forceinline__ int unpackI(ull p){ return 8191 - (int)(p & 0x1FFFull); }

// ---- kW: weight precompute + tail zero (runs once)
__global__ void kW(const void* __restrict__ ev, const void* __restrict__ Wq,
                   const void* __restrict__ Wk, const void* __restrict__ Wpe,
                   const void* __restrict__ w1, float* __restrict__ ws, int tail){
  const bool bf = isbf(ev);
  const int tid = threadIdx.x;  // 256
  for (int i = tid; i < TT_ZCNT; i += 256) ws[tail + TT_ZOFF + i] = 0.f;
  if (tid < 64){
    float s1 = 0.f, s2 = 0.f;
    for (int c = 0; c < 64; c++){
      float wc = ld(w1, c, bf);
      s1 += ld(Wq, tid*64 + c, bf) * wc;
      s2 += ld(Wk, tid*64 + c, bf) * wc;
    }
    ws[tail + TT_W1 + tid] = s1;
    ws[tail + TT_W1 + 64 + tid] = s2;
    if (tid < 4){
      float s3 = 0.f;
      for (int c = 0; c < 64; c++) s3 += ld(Wpe, tid*64 + c, bf) * ld(w1, c, bf);
      ws[tail + TT_W1 + 128 + tid] = s3;
    }
  }
}

// ---- kE: ESUM[bb][i] = sum_n events[bb,n,i]
__global__ void __launch_bounds__(256) kE(const void* __restrict__ ev,
    float* __restrict__ ws, int tail, int bb0){
  const bool bf = isbf(ev);
  const int bb = bb0 + blockIdx.z;
  const int lane = threadIdx.x & 63, w = threadIdx.x >> 6;
  float s0 = 0.f, s1 = 0.f, s2 = 0.f, s3 = 0.f;
#pragma unroll
  for (int j = 0; j < 4; j++){
    int r = blockIdx.x*256 + threadIdx.x + 2048*j;
    const int e4 = (bb*NB + r)*4;
    s0 += ld(ev, e4+0, bf); s1 += ld(ev, e4+1, bf);
    s2 += ld(ev, e4+2, bf); s3 += ld(ev, e4+3, bf);
  }
  s0 = waveSum(s0); s1 = waveSum(s1); s2 = waveSum(s2); s3 = waveSum(s3);
  __shared__ float r4[4][4];
  if (lane == 0){ r4[w][0]=s0; r4[w][1]=s1; r4[w][2]=s2; r4[w][3]=s3; }
  __syncthreads();
  if (threadIdx.x < 4)
    atomicAdd(&ws[tail + TT_ESUM + bb*16 + threadIdx.x],
              r4[0][threadIdx.x]+r4[1][threadIdx.x]+r4[2][threadIdx.x]+r4[3][threadIdx.x]);
}

// ---- kA: 1024 blocks/batch, 8 rows each
__global__ void __launch_bounds__(256, 4) kA(const void* __restrict__ ev,
    const void* __restrict__ Wm, const void* __restrict__ Wpe,
    const void* __restrict__ Wv, float* __restrict__ ws,
    int offA, int strA, int tail, int bb0){
  const bool bf = isbf(ev);
  const int bb = bb0 + blockIdx.z;
  const int lane = threadIdx.x & 63, w = threadIdx.x >> 6;
  float* A = ws + offA + (size_t)bb*strA;
  const float wq1 = ws[tail + TT_W1 + lane];
  const float wk1 = ws[tail + TT_W1 + 64 + lane];
  const float wp10 = ws[tail+TT_W1+128], wp11 = ws[tail+TT_W1+129],
              wp12 = ws[tail+TT_W1+130], wp13 = ws[tail+TT_W1+131];
  float wmc[4];
#pragma unroll
  for (int j = 0; j < 4; j++) wmc[j] = ld(Wm, j*64+lane, bf);
  const bool edgeBlk = (blockIdx.x == 0 || blockIdx.x == 1023);
  float wpc[4], wvc[64];
  if (edgeBlk){
#pragma unroll
    for (int j = 0; j < 4; j++) wpc[j] = ld(Wpe, j*64+lane, bf);
#pragma unroll
    for (int cn = 0; cn < 64; cn++) wvc[cn] = ld(Wv, cn*64+lane, bf);
  }
#pragma unroll
  for (int i = 0; i < 2; i++){
    const int n = blockIdx.x*8 + w + 4*i;
    const int e4 = (bb*NB + n)*4;
    float e0 = ld(ev, e4+0, bf), e1 = ld(ev, e4+1, bf),
          e2 = ld(ev, e4+2, bf), e3 = ld(ev, e4+3, bf);
    float lx = e0*wmc[0] + e1*wmc[1] + e2*wmc[2] + e3*wmc[3];
    float epe = e0*wp10 + e1*wp11 + e2*wp12 + e3*wp13;
    float acv = waveSum(lx * wq1) + epe;
    float tv  = waveSum(lx * wk1) + epe;
    A[n*64 + lane] = lx;
    if (lane == 0){
      ws[tail + TT_AC + bb*8192 + n] = acv;
      ws[tail + TT_T  + bb*8192 + n] = tv;
    }
    if (edgeBlk && (n < 8 || n >= NB-8)){
      int e = (n < 8) ? n : (n - (NB-16));
      float v = 0.f;
#pragma unroll
      for (int cn = 0; cn < 64; cn++) v += __shfl(lx, cn, 64) * wvc[cn];
      float f = e0*wpc[0] + e1*wpc[1] + e2*wpc[2] + e3*wpc[3];
      ws[tail + TT_EDGEV + bb*1024 + e*64 + lane] = v;
      ws[tail + TT_EDGEF + bb*1024 + e*64 + lane] = f;
    }
  }
}

// ---- kB: VSUM from ESUM algebra; S[m,c]
__global__ void __launch_bounds__(64) kB(const void* __restrict__ ev,
    const void* __restrict__ Wm, const void* __restrict__ Wv,
    float* __restrict__ ws, int tail, int bb0){
  const bool bf = isbf(ev);
  const int bb = bb0 + blockIdx.z;
  const int m = blockIdx.x, lane = threadIdx.x;
  float tm = 0.f;
#pragma unroll
  for (int i = 0; i < 4; i++) tm += ws[tail + TT_ESUM + bb*16 + i] * ld(Wm, i*64 + lane, bf);
  float vs0 = 0.f, vs1 = 0.f;
#pragma unroll
  for (int j = 0; j < 64; j += 2){
    vs0 += __shfl(tm, j, 64)   * ld(Wv, j*64 + lane, bf);
    vs1 += __shfl(tm, j+1, 64) * ld(Wv, (j+1)*64 + lane, bf);
  }
  float vsum = vs0 + vs1;
  const int d = m - 8;
  float sv = 0.f, sf = 0.f;
  const float* EV = ws + tail + TT_EDGEV + bb*1024;
  const float* EF = ws + tail + TT_EDGEF + bb*1024;
  if (d < 0){
    for (int e = 16 + d; e < 16; e++){ sv += EV[e*64+lane]; sf += EF[e*64+lane]; }
  } else {
    for (int e = 0; e < d; e++){ sv += EV[e*64+lane]; sf += EF[e*64+lane]; }
  }
  ws[tail + TT_S + bb*1024 + m*64 + lane] = vsum - sv + sf;
}

// ---- kC: softmax + lx_out + kg/vg + LXP partials
__global__ void __launch_bounds__(256, 4) kC(const void* __restrict__ ev,
    const void* __restrict__ Wsa2, const void* __restrict__ gWk,
    const void* __restrict__ gWv, float* __restrict__ ws,
    int offA, int strA, int offB, int strB, int offC, int strC,
    int offLXP, int strLXP, int tail, int bb0){
  const bool bf = isbf(ev);
  const int bb = bb0 + blockIdx.z;
  float* A = ws + offA + (size_t)bb*strA;
  float* Bp = ws + offB + (size_t)bb*strB;
  float* Cp = ws + offC + (size_t)bb*strC;
  __shared__ float S_lds[1024];
  __shared__ float lred[4][64];
  const int tid = threadIdx.x, lane = tid & 63, w = tid >> 6;
  for (int i = tid; i < 1024; i += 256) S_lds[i] = ws[tail + TT_S + bb*1024 + i];
  __syncthreads();
  float wcol[64];
#pragma unroll
  for (int cn = 0; cn < 64; cn++) wcol[cn] = ld(Wsa2, cn*64 + lane, bf);
  float lxoR[2];
  float lxsum = 0.f;
#pragma unroll
  for (int i = 0; i < 2; i++){
    const int n = blockIdx.x*8 + w + 4*i;
    float lx  = A[n*64 + lane];
    float acn = ws[tail + TT_AC + bb*8192 + n];
    const int m = lane & 15;
    const int j = n + m - 8;
    float tv = (j >= 0 && j < NB) ? ws[tail + TT_T + bb*8192 + j] : 0.f;
    float logit = acn - tv;
    float mx = logit;
#pragma unroll
    for (int k = 1; k < 16; k <<= 1) mx = fmaxf(mx, __shfl_xor(mx, k, 64));
    float ex = expf(logit - mx);
    float sm = ex;
#pragma unroll
    for (int k = 1; k < 16; k <<= 1) sm += __shfl_xor(sm, k, 64);
    float sig = ex / sm;
    float pat = 0.f;
#pragma unroll
    for (int mm = 0; mm < 16; mm++) pat += __shfl(sig, mm, 64) * S_lds[mm*64 + lane];
    float sa0 = 0.f, sa1 = 0.f;
#pragma unroll
    for (int cn = 0; cn < 64; cn += 2){
      sa0 += __shfl(pat, cn, 64)   * wcol[cn];
      sa1 += __shfl(pat, cn+1, 64) * wcol[cn+1];
    }
    float lxo = lx + sa0 + sa1;
    lxoR[i] = lxo;
    Bp[n*64 + lane] = lxo;
    lxsum += lxo;
  }
  lred[w][lane] = lxsum;
#pragma unroll
  for (int cn = 0; cn < 64; cn++) wcol[cn] = ld(gWk, cn*64 + lane, bf);
#pragma unroll
  for (int i = 0; i < 2; i++){
    const int n = blockIdx.x*8 + w + 4*i;
    float k0 = 0.f, k1 = 0.f;
#pragma unroll
    for (int cn = 0; cn < 64; cn += 2){
      k0 += __shfl(lxoR[i], cn, 64)   * wcol[cn];
      k1 += __shfl(lxoR[i], cn+1, 64) * wcol[cn+1];
    }
    A[n*64 + lane] = k0 + k1;
  }
#pragma unroll
  for (int cn = 0; cn < 64; cn++) wcol[cn] = ld(gWv, cn*64 + lane, bf);
#pragma unroll
  for (int i = 0; i < 2; i++){
    const int n = blockIdx.x*8 + w + 4*i;
    float v0 = 0.f, v1 = 0.f;
#pragma unroll
    for (int cn = 0; cn < 64; cn += 2){
      v0 += __shfl(lxoR[i], cn, 64)   * wcol[cn];
      v1 += __shfl(lxoR[i], cn+1, 64) * wcol[cn+1];
    }
    Cp[n*64 + lane] = v0 + v1;
  }
  __syncthreads();
  if (tid < 64)
    ws[offLXP + (size_t)bb*strLXP + blockIdx.x*64 + tid] =
      lred[0][tid]+lred[1][tid]+lred[2][tid]+lred[3][tid];
}

// ---- kFPS: grid (8,3,nb). Leaderless single-cacheline slot barrier.
__global__ void __launch_bounds__(512) kFPS(const void* __restrict__ ev,
    const void* __restrict__ gWk, const void* __restrict__ gWv,
    const void* __restrict__ gWpe, const void* __restrict__ gWsa1,
    const void* __restrict__ gWsa2, float* __restrict__ ws,
    int offA, int strA, int offB, int strB, int offC, int strC,
    int offLXP, int strLXP, int tail, int bb0){
  const int g = blockIdx.y, idx = blockIdx.x;
  const int bb = bb0 + blockIdx.z;
  const int tid = threadIdx.x, lane = tid & 63, w = tid >> 6;
  const float* pts = ws + (g == 0 ? offB + (size_t)bb*strB
                         : g == 1 ? offA + (size_t)bb*strA
                                  : offC + (size_t)bb*strC);
  ull* slot = (ull*)(ws + tail + TT_SYNC + (bb*3 + g)*32);  // [par*8+blk]
  int* gcnt = (int*)(ws + tail + TT_GCNT + bb*16);

  __shared__ float cent[64];
  __shared__ float red[8][64];
  __shared__ float lxsS[64];
  __shared__ ull   wvS[8];
  __shared__ int   selS[16];
  __shared__ int   sCur;
  __shared__ float gfS[1024];
  __shared__ float betaS[16];
  __shared__ float GS[64];

  const int n0 = idx*1024 + tid;       // +0 and +512
  float4 P[2][16];
#pragma unroll
  for (int j = 0; j < 2; j++)
#pragma unroll
    for (int i = 0; i < 16; i++)
      P[j][i] = ((const float4*)(pts + (size_t)(n0 + j*512)*64))[i];

  // head: LXSUM from 1024 partials; cent analytically per group
  {
    const int c = tid & 63, grp = tid >> 6;
    float s = 0.f;
    const float* LXP = ws + offLXP + (size_t)bb*strLXP;
    for (int b2 = grp; b2 < 1024; b2 += 8) s += LXP[b2*64 + c];
    red[grp][c] = s;
  }
  __syncthreads();
  const bool bf = isbf(ev);
  if (tid < 64){
    float lxs = 0.f;
#pragma unroll
    for (int q = 0; q < 8; q++) lxs += red[q][tid];
    lxsS[tid] = lxs;
    float c;
    if (g == 0) c = lxs * (1.0f/NB);
    else {
      const void* W = (g == 1) ? gWk : gWv;
      float s = 0.f;
#pragma unroll
      for (int j = 0; j < 64; j++) s += __shfl(lxs, j, 64) * ld(W, j*64 + tid, bf);
      c = s * (1.0f/NB);
    }
    cent[tid] = c;
  }
  __syncthreads();

  const float4* cv = (const float4*)cent;
  float md[2] = {1e10f, 1e10f};
  int cur;

  // phase 1: farthest0 (dist to bary, no md update)
  {
    float dd[2];
#pragma unroll
    for (int j = 0; j < 2; j++){
      float d = 0.f;
#pragma unroll
      for (int i = 0; i < 16; i++){
        float4 c = cv[i];
        float dx = P[j][i].x-c.x, dy = P[j][i].y-c.y, dz = P[j][i].z-c.z, dw = P[j][i].w-c.w;
        d += dx*dx; d += dy*dy; d += dz*dz; d += dw*dw;
      }
      dd[j] = d;
    }
    ull p0 = packPDI(1, dd[0], n0);
    ull p1 = packPDI(1, dd[1], n0 + 512);
    ull bp = waveMaxU64(p0 > p1 ? p0 : p1);
    if (lane == 0) wvS[w] = bp;
    __syncthreads();
    if (w == 0){
      ull v = (lane < 8) ? wvS[lane] : 0;
#pragma unroll
      for (int m = 1; m < 8; m <<= 1){
        ull o = (ull)__shfl_xor((long long)v, m, 64);
        if (o > v) v = o;
      }
      if (lane == 0)
        __hip_atomic_store(&slot[(1&1)*8 + idx], v, __ATOMIC_RELEASE, __HIP_MEMORY_SCOPE_AGENT);
      ull got;
      for (;;){
        got = (lane < 8) ? __hip_atomic_load(&slot[(1&1)*8 + lane], __ATOMIC_RELAXED, __HIP_MEMORY_SCOPE_AGENT) : 0;
        ull ok = __ballot(lane >= 8 || (int)(got >> 45) == 1);
        if (ok == ~0ull) break;
        __builtin_amdgcn_s_sleep(1);
      }
#pragma unroll
      for (int m = 1; m < 8; m <<= 1){
        ull o = (ull)__shfl_xor((long long)got, m, 64);
        if (o > got) got = o;
      }
      if (lane == 0) sCur = unpackI(got);
    }
    __syncthreads();
    cur = sCur;
  }

  for (int it = 0; ; it++){
    if (tid == 0) selS[it] = cur;
    if (it == 15) break;
    if (tid < 16) ((float4*)cent)[tid] = ((const float4*)(pts + (size_t)cur*64))[tid];
    __syncthreads();
    const int phase = it + 2;
    float dd[2];
#pragma unroll
    for (int j = 0; j < 2; j++){
      float d = 0.f;
#pragma unroll
      for (int i = 0; i < 16; i++){
        float4 c = cv[i];
        float dx = P[j][i].x-c.x, dy = P[j][i].y-c.y, dz = P[j][i].z-c.z, dw = P[j][i].w-c.w;
        d += dx*dx; d += dy*dy; d += dz*dz; d += dw*dw;
      }
      md[j] = fminf(md[j], d);
      dd[j] = md[j];
    }
    ull p0 = packPDI(phase, dd[0], n0);
    ull p1 = packPDI(phase, dd[1], n0 + 512);
    ull bp = waveMaxU64(p0 > p1 ? p0 : p1);
    if (lane == 0) wvS[w] = bp;
    __syncthreads();
    const int par = phase & 1;
    if (w == 0){
      ull v = (lane < 8) ? wvS[lane] : 0;
#pragma unroll
      for (int m = 1; m < 8; m <<= 1){
        ull o = (ull)__shfl_xor((long long)v, m, 64);
        if (o > v) v = o;
      }
      if (lane == 0)
        __hip_atomic_store(&slot[par*8 + idx], v, __ATOMIC_RELEASE, __HIP_MEMORY_SCOPE_AGENT);
      ull got;
      for (;;){
        got = (lane < 8) ? __hip_atomic_load(&slot[par*8 + lane], __ATOMIC_RELAXED, __HIP_MEMORY_SCOPE_AGENT) : 0;
        ull ok = __ballot(lane >= 8 || (int)(got >> 45) == phase);
        if (ok == ~0ull) break;
        __builtin_amdgcn_s_sleep(1);
      }
#pragma unroll
      for (int m = 1; m < 8; m <<= 1){
        ull o = (ull)__shfl_xor((long long)got, m, 64);
        if (o > got) got = o;
      }
      if (lane == 0) sCur = unpackI(got);
    }
    __syncthreads();
    cur = sCur;
  }
  __syncthreads();

  if (idx == 0){
    if (tid == 0){
      for (int i = 1; i < 16; i++){
        int key = selS[i]; int j = i - 1;
        while (j >= 0 && selS[j] > key){ selS[j+1] = selS[j]; j--; }
        selS[j+1] = key;
      }
    }
    __syncthreads();
    for (int idx2 = tid; idx2 < 1024; idx2 += 512)
      ws[tail + TT_SEL + bb*3072 + g*1024 + idx2] = pts[(size_t)selS[idx2 >> 6]*64 + (idx2 & 63)];
    __threadfence();
  }
  __syncthreads();
  if (tid == 0) atomicAdd(gcnt, 1);
  if (g != 0 || idx != 0) return;

  // ---- kG tail (per batch)
  if (tid == 0){
    while (__hip_atomic_load(gcnt, __ATOMIC_RELAXED, __HIP_MEMORY_SCOPE_AGENT) < 24)
      __builtin_amdgcn_s_sleep(1);
    __threadfence();
  }
  __syncthreads();
  if (tid < 64){
    const float gw1 = ld(gWsa1, tid, bf);
    float wpec[64];
#pragma unroll
    for (int cn = 0; cn < 64; cn++) wpec[cn] = ld(gWpe, cn*64 + tid, bf);
    float lxs = lxsS[tid];
    float G = 0.f;
#pragma unroll
    for (int cn = 0; cn < 64; cn++) G += __shfl(lxs, cn, 64) * wpec[cn];
    GS[tid] = G;
    const float* selp = ws + tail + TT_SEL + bb*3072;
    for (int m = 0; m < 16; m++){
      float plx = selp[m*64 + tid];
      float g2 = 0.f;
#pragma unroll
      for (int cn = 0; cn < 64; cn++) g2 += __shfl(plx, cn, 64) * wpec[cn];
      gfS[m*64 + tid] = g2;
      float pkv = selp[1024 + m*64 + tid];
      float part = waveSum((pkv + g2) * gw1);
      if (tid == 0) betaS[m] = part;
    }
  }
  __syncthreads();
  if (tid < 64){
    float mx = -1e30f;
    for (int m = 0; m < 16; m++) mx = fmaxf(mx, -betaS[m]);
    float ssum = 0.f;
    for (int m = 0; m < 16; m++) ssum += expf(-betaS[m] - mx);
    float A = 0.f;
    for (int m = 0; m < 16; m++){
      float sg = expf(-betaS[m] - mx) / ssum;
      float pv = ws[tail + TT_SEL + bb*3072 + 2048 + m*64 + tid];
      float Sg = 8192.0f * (pv - gfS[m*64 + tid]) + GS[tid];
      A += sg * Sg;
    }
    float cg = 0.f;
#pragma unroll
    for (int cn = 0; cn < 64; cn++) cg += __shfl(A, cn, 64) * ld(gWsa2, cn*64 + tid, bf);
    ws[tail + TT_CG + bb*64 + tid] = cg;
  }
}

// ---- kZeroSpace: grid (2700,1,nb)
__global__ void kZeroSpace(float* __restrict__ ws, int offSp, int strSp, int bb0){
  const int bb = bb0 + blockIdx.z;
  float4 z = make_float4(0.f, 0.f, 0.f, 0.f);
  ((float4*)(ws + offSp + (size_t)bb*strSp))[blockIdx.x*256 + threadIdx.x] = z;
}

// ---- kImg: LN + GELU + scatter-add
__global__ void __launch_bounds__(256, 4) kImg(const void* __restrict__ ev,
    const void* __restrict__ lnw, const void* __restrict__ lnb,
    float* __restrict__ ws, int offB, int strB, int offSp, int strSp,
    int tail, int bb0){
  const bool bf = isbf(ev);
  const int bb = bb0 + blockIdx.z;
  const int lane = threadIdx.x & 63, w = threadIdx.x >> 6;
  const float cg = ws[tail + TT_CG + bb*64 + lane];
  const float lw = ld(lnw, lane, bf), lb = ld(lnb, lane, bf);
  float* space = ws + offSp + (size_t)bb*strSp;
  const float* Bp = ws + offB + (size_t)bb*strB;
#pragma unroll
  for (int i = 0; i < 2; i++){
    const int n = blockIdx.x*8 + w + 4*i;
    float x = Bp[n*64 + lane] + cg;
    float mu = waveSum(x) * (1.0f/64.0f);
    float dv = x - mu;
    float var = waveSum(dv*dv) * (1.0f/64.0f);
    float xn = dv / sqrtf(var + 1e-5f);
    float y = xn * lw + lb;
    float h = 0.5f * y * (1.0f + erff(y * 0.70710678118654752f));
    const int e4 = (bb*NB + n)*4;
    float exf = ld(ev, e4+0, bf), eyf = ld(ev, e4+1, bf), epf = ld(ev, e4+3, bf);
    int xi = (int)floorf(exf), yi = (int)floorf(eyf);
    int flat = yi*IMG_W + xi;
    flat = max(0, min(HWPIX-1, flat));
    atomicAdd(space + flat*64 + lane, epf * h);
  }
}

// ---- kStat: cnt,sum,sumsq per batch
__global__ void __launch_bounds__(256) kStat(float* __restrict__ ws,
    int offSp, int strSp, int tail, int bb0){
  const int bb = bb0 + blockIdx.z;
  const float4* sp = (const float4*)(ws + offSp + (size_t)bb*strSp);
  float cnt = 0.f, sum = 0.f, ssq = 0.f;
  for (unsigned i = blockIdx.x*256u + threadIdx.x; i < SPB/4; i += 65536u){
    float4 v = sp[i];
    if (v.x != 0.f){ cnt += 1.f; sum += v.x; ssq += v.x*v.x; }
    if (v.y != 0.f){ cnt += 1.f; sum += v.y; ssq += v.y*v.y; }
    if (v.z != 0.f){ cnt += 1.f; sum += v.z; ssq += v.z*v.z; }
    if (v.w != 0.f){ cnt += 1.f; sum += v.w; ssq += v.w*v.w; }
  }
  cnt = waveSum(cnt); sum = waveSum(sum); ssq = waveSum(ssq);
  __shared__ float rc[4], rs[4], rq[4];
  const int lane = threadIdx.x & 63, w = threadIdx.x >> 6;
  if (lane == 0){ rc[w] = cnt; rs[w] = sum; rq[w] = ssq; }
  __syncthreads();
  if (threadIdx.x == 0){
    atomicAdd(&ws[tail + TT_STATS + bb*16 + 0], rc[0]+rc[1]+rc[2]+rc[3]);
    atomicAdd(&ws[tail + TT_STATS + bb*16 + 1], rs[0]+rs[1]+rs[2]+rs[3]);
    atomicAdd(&ws[tail + TT_STATS + bb*16 + 2], rq[0]+rq[1]+rq[2]+rq[3]);
  }
}

// ---- kOut: LDS-transpose 64hw x 64c; var from sum/sumsq
__global__ void __launch_bounds__(256) kOut(const void* __restrict__ ev,
    const float* __restrict__ ws, void* __restrict__ out,
    int offSp, int strSp, int tail, int bb0){
  const bool bf = isbf(ev);
  const int bb = bb0 + blockIdx.z;
  __shared__ float tile[64*64];
  const int tid = threadIdx.x;
  const int hw0 = blockIdx.x*64;
  const float* sp = ws + offSp + (size_t)bb*strSp;
#pragma unroll
  for (int i = 0; i < 16; i++){
    int idx = tid + 256*i;
    tile[idx] = sp[(size_t)hw0*64 + idx];
  }
  const float cnt = ws[tail + TT_STATS + bb*16 + 0];
  const float sum = ws[tail + TT_STATS + bb*16 + 1];
  const float ssq = ws[tail + TT_STATS + bb*16 + 2];
  const float mean = sum / fmaxf(cnt, 1.f);
  const float m2   = fmaxf(ssq - sum*mean, 0.f);
  const float var  = m2 / fmaxf(cnt - 1.f, 1.f);
  const float stdv = sqrtf(var);
  __syncthreads();
  const int c = tid >> 2, sub = tid & 3;
#pragma unroll
  for (int j = 0; j < 16; j++){
    int hwl = sub*16 + j;
    float x = tile[hwl*64 + c];
    float centered = (x != 0.f) ? (x - mean) : x;
    float normed = (stdv > 0.f) ? (centered / stdv) : centered;
    float o = (cnt > 0.f) ? normed : x;
    stout(out, (long)(bb*64 + c)*HWPIX + hw0 + hwl, o, bf);
  }
}

extern "C" void kernel_launch(void* const* d_in, const int* in_sizes, int n_in,
                              void* d_out, int out_size, void* d_ws, size_t ws_size,
                              hipStream_t stream){
  (void)in_sizes; (void)n_in; (void)out_size;
  const void* ev     = d_in[0];
  const void* Wm     = d_in[1];
  const void* Wpe    = d_in[2];
  const void* lnw    = d_in[3];
  const void* lnb    = d_in[4];
  const void* lxWq   = d_in[5];
  const void* lxWk   = d_in[6];
  const void* lxWv   = d_in[7];
  const void* lxWsa1 = d_in[8];
  const void* lxWsa2 = d_in[9];
  // d_in[10] = gx_Wq : unused (cancels in n-independent softmax)
  const void* gxWk   = d_in[11];
  const void* gxWv   = d_in[12];
  const void* gxWpe  = d_in[13];
  const void* gxWsa1 = d_in[14];
  const void* gxWsa2 = d_in[15];
  float* ws = (float*)d_ws;

  // Parallel layout: B[2NC] | SPACE[2SPB] (aliases A,C,LXP) | tail
  const int P_TAIL = 2*NC + 2*SPB;
  const size_t PAR_BYTES = (size_t)(P_TAIL + TT_TOT) * 4;
  const bool par = ws_size >= PAR_BYTES;

  int offB, strB, offSp, strSp, offA, strA, offC, strC, offLXP, strLXP, tail;
  if (par){
    offB = 0;        strB = NC;
    offSp = 2*NC;    strSp = SPB;
    offA = 2*NC;     strA = NC;
    offC = 4*NC;     strC = NC;
    offLXP = 6*NC;   strLXP = 65536;
    tail = P_TAIL;
  } else {
    // Sequential layout: SPACE[SPB] (aliases A,C,LXP) | B[NC] | tail
    offSp = 0;       strSp = 0;
    offA = 0;        strA = 0;
    offC = NC;       strC = 0;
    offLXP = 2*NC;   strLXP = 0;
    offB = SPB;      strB = 0;
    tail = SPB + NC;
  }
  const int nb = par ? 2 : 1;
  const int iters = par ? 1 : 2;

  kW<<<1, 256, 0, stream>>>(ev, lxWq, lxWk, Wpe, lxWsa1, ws, tail);
  for (int t = 0; t < iters; t++){
    const int bb0 = par ? 0 : t;
    kE<<<dim3(8,1,nb), 256, 0, stream>>>(ev, ws, tail, bb0);
    kA<<<dim3(1024,1,nb), 256, 0, stream>>>(ev, Wm, Wpe, lxWv, ws, offA, strA, tail, bb0);
    kB<<<dim3(16,1,nb), 64, 0, stream>>>(ev, Wm, lxWv, ws, tail, bb0);
    kC<<<dim3(1024,1,nb), 256, 0, stream>>>(ev, lxWsa2, gxWk, gxWv, ws,
        offA, strA, offB, strB, offC, strC, offLXP, strLXP, tail, bb0);
    kFPS<<<dim3(8,3,nb), 512, 0, stream>>>(ev, gxWk, gxWv, gxWpe, gxWsa1, gxWsa2, ws,
        offA, strA, offB, strB, offC, strC, offLXP, strLXP, tail, bb0);
    kZeroSpace<<<dim3(2700,1,nb), 256, 0, stream>>>(ws, offSp, strSp, bb0);
    kImg<<<dim3(1024,1,nb), 256, 0, stream>>>(ev, lnw, lnb, ws, offB, strB, offSp, strSp, tail, bb0);
    kStat<<<dim3(256,1,nb), 256, 0, stream>>>(ws, offSp, strSp, tail, bb0);
    kOut<<<dim3(675,1,nb), 256, 0, stream>>>(ev, ws, d_out, offSp, strSp, tail, bb0);
  }
}